// Round 6
// baseline (5191.323 us; speedup 1.0000x reference)
//
#include <hip/hip_runtime.h>
#include <stdint.h>

#define LOG2E 1.44269504088896340736f

struct LtcArgs {
  const float *x, *c1w, *c1b, *c2w, *c2b;
  const float *g1,*vl1,*cm1,*sg1,*mu1,*w1,*er1,*ssg1,*smu1,*sw1,*ser1,*iw1,*ib1,*ow1,*ob1;
  const void  *mk1,*smk1;
  const float *g2,*vl2,*cm2,*sg2,*mu2,*w2,*er2,*ssg2,*smu2,*sw2,*ser2,*iw2,*ib2,*ow2,*ob2;
  const void  *mk2,*smk2;
  const float *fcw,*fcb;
  float *out;
};

__device__ __forceinline__ float fexp2(float v){ return __builtin_amdgcn_exp2f(v); }
__device__ __forceinline__ float frcp (float v){ return __builtin_amdgcn_rcpf(v); }
__device__ __forceinline__ int wave_max(int v){
  #pragma unroll
  for (int s=1;s<64;s<<=1){ int o=__shfl_xor(v,s); v = o>v ? o : v; }
  return __builtin_amdgcn_readfirstlane(v);
}

// ---- mask dtype detection (verified: absmax 0) ----
__device__ __forceinline__ void scan_mask(const void* p, int n, int tid, int* cge2, int* cone){
  const uint8_t* bp = (const uint8_t*)p;
  int g=0,o=0;
  for (int k=tid;k<n;k+=256){ uint8_t v=bp[k]; g += (v>=2); o += (v==1); }
  if (g) atomicAdd(cge2,g);
  if (o) atomicAdd(cone,o);
}
__device__ __forceinline__ int decide_mode(int ge2,int one,int n){
  if (ge2 > (n>>4)) return 2;
  if (one > (n>>2)) return 0;
  return 1;
}
__device__ __forceinline__ float mask_at(const void* p,int mode,int idx){
  if (mode==2) return ((const float*)p)[idx]!=0.f ? 1.f:0.f;
  if (mode==1) return ((const int*)p)[idx]!=0 ? 1.f:0.f;
  return ((const uint8_t*)p)[idx]!=0 ? 1.f:0.f;
}

// ================= kernel 0: mask modes -> hdr =================
__global__ void ltc_modes(const void* mk1,const void* smk1,const void* mk2,const void* smk2,int* hdr){
  __shared__ int cnt[8];
  const int tid=threadIdx.x;
  if (tid<8) cnt[tid]=0;
  __syncthreads();
  scan_mask(mk1, 4096, tid, &cnt[0], &cnt[1]);
  scan_mask(smk1,2048, tid, &cnt[2], &cnt[3]);
  scan_mask(mk2, 1024, tid, &cnt[4], &cnt[5]);
  scan_mask(smk2,1024, tid, &cnt[6], &cnt[7]);
  __syncthreads();
  if (tid==0){
    hdr[0]=decide_mode(cnt[0],cnt[1],4096);
    hdr[1]=decide_mode(cnt[2],cnt[3],2048);
    hdr[2]=decide_mode(cnt[4],cnt[5],1024);
    hdr[3]=decide_mode(cnt[6],cnt[7],1024);
  }
}

// ================= kernel 1: precompute conv + L1 synapse sums =================
__global__ __launch_bounds__(256,2)
void ltc_pre(LtcArgs a, const int* __restrict__ hdr, float2* __restrict__ pre)
{
  const int b=blockIdx.x, tb=blockIdx.y*64, tid=threadIdx.x;
  const int mds1=hdr[1];
  __shared__ float us[4][32];

  const int j = tid&63;
  float As[32],Bs[32],Ws[32],Es[32];
  #pragma unroll
  for (int e=0;e<32;e++){
    const int idx=e*64+j;
    const float s=a.ssg1[idx];
    As[e]=-s*LOG2E; Bs[e]=s*a.smu1[idx]*LOG2E;
    const float wm=a.sw1[idx]*mask_at(a.smk1,mds1,idx);
    Ws[e]=wm; Es[e]=wm*a.ser1[idx];
  }
  const int th=tid>>5, f=tid&31, cc=f>>2, cwp=f&3;
  float k1[12],b1[4],k2[12],cb2=0.f,wi=0.f,bi=0.f;
  if (tid<128){
    #pragma unroll
    for (int q=0;q<12;q++) k1[q]=a.c1w[q];
    #pragma unroll
    for (int q=0;q<4;q++)  b1[q]=a.c1b[q];
    #pragma unroll
    for (int q=0;q<12;q++) k2[q]=a.c2w[cc*12+q];
    cb2=a.c2b[cc]; wi=a.iw1[f]; bi=a.ib1[f];
  }

  for (int tt=0; tt<64; tt+=4){
    if (tid<128){
      const int t=tb+tt+th;
      const float4* xg=(const float4*)(a.x + ((size_t)b*1024 + t)*8);
      float4 xa=xg[0], xb=xg[1];
      float xr[8]={xa.x,xa.y,xa.z,xa.w,xb.x,xb.y,xb.z,xb.w};
      float acc=cb2;
      #pragma unroll
      for (int ci=0;ci<4;ci++){
        const float q0=k1[ci*3],q1=k1[ci*3+1],q2=k1[ci*3+2],bb=b1[ci];
        #pragma unroll
        for (int kk=0;kk<3;kk++){
          const int p=cwp+kk;
          float h=fmaf(q0,xr[p],fmaf(q1,xr[p+1],fmaf(q2,xr[p+2],bb)));
          h=fmaxf(h,0.f);
          acc=fmaf(k2[ci*3+kk],h,acc);
        }
      }
      us[th][f]=fmaf(acc,wi,bi);
    }
    __syncthreads();
    {
      const int t4=tid>>6;
      float wns=0.f,wds=0.f;
      #pragma unroll
      for (int e=0;e<32;e++){
        const float u=us[t4][e];
        const float z=fmaf(As[e],u,Bs[e]);
        const float sg=frcp(1.f+fexp2(z));
        wds=fmaf(Ws[e],sg,wds);
        wns=fmaf(Es[e],sg,wns);
      }
      pre[((size_t)((b<<10)+tb+tt+t4))*64 + j] = make_float2(wns,wds);
    }
    __syncthreads();
  }
}

// ================= kernel 2: sequential scan, group-local shfl reduce =================
// 256 blocks x 512 thr. 8-lane lane-groups OWN one neuron each: wave w lane l
// handles L1 neuron j1=(w<<3)|(l>>3), sub-slot l&7 takes ranks == sub (mod 8)
// of that neuron's mask column (<=8 slots, exact for nnz<=64; 4 uncond + tail
// guarded by c1max). Reduce = 3 shfl_xor levels intra-group (no LDS partial
// arrays, no replicated readback, no serial reducer wave). All 8 lanes compute
// identical v1; same-value write into double-buffered v1u[2][64] (read p,
// write p^1) -> ONE barrier per segment. L2 (32 neurons) identical scheme on
// lanes 0-31 (j2=(w<<2)|(l>>3), <=4 slots), one timestep behind, with the
// verified sensory-fold; unfold-5-of-(t-2) at k==0 uses OLD bn2 BEFORE the
// sensory reduce overwrites it. R3 lesson: no LDS float atomics. R4 lesson:
// no serial reducer phase.
__global__ __launch_bounds__(512,1)
void ltc_scan(LtcArgs a, const float2* __restrict__ pre, const int* __restrict__ hdr)
{
  const int b=blockIdx.x, tid=threadIdx.x;
  const int w=tid>>6, l=tid&63;
  const int g=l>>3, sub=l&7;
  const int j1=(w<<3)|g;                 // L1 neuron owned by this 8-lane group
  const bool L2a=(l<32);
  const int j2=(w<<2)|(g&3);             // L2 neuron (lanes 0-31)

  __shared__ float v1u[2][64];
  __shared__ float v2u[2][32];
  __shared__ float v1fin[64];

  if (tid<64){ v1u[0][tid]=0.f; v1u[1][tid]=0.f; v1fin[tid]=0.f; }
  else if (tid<96){ v2u[0][tid-64]=0.f; v2u[1][tid-64]=0.f; }

  const int md1=hdr[0], md2=hdr[2], mds2=hdr[3];

  // ---- L1 slots: ranks == sub (mod 8) of column j1, cap 8 (exact) ----
  float A[8],B[8],W[8],E[8]; int I[8];
  #pragma unroll
  for (int q=0;q<8;q++){ A[q]=0.f;B[q]=0.f;W[q]=0.f;E[q]=0.f;I[q]=0; }
  int c1max=0;
  {
    int r=0, cnt=0;
    for (int e=0;e<64;e++){
      if (mask_at(a.mk1,md1,e*64+j1)!=0.f){
        if ((r&7)==sub && cnt<8){
          const int idx=e*64+j1;
          const float s=a.sg1[idx];
          A[cnt]=-s*LOG2E; B[cnt]=s*a.mu1[idx]*LOG2E;
          const float wmv=a.w1[idx];
          W[cnt]=wmv; E[cnt]=wmv*a.er1[idx];
          I[cnt]=e;
          cnt++;
        }
        r++;
      }
    }
    c1max = wave_max(cnt);
  }

  // ---- L2 slots (lanes 0-31): ranks == sub (mod 8) of column j2, cap 4 ----
  float A2[4],B2[4],W2[4],E2[4]; int I2[4];
  float As2[4],Bs2[4],Ws2[4],Es2[4]; int Is2[4];
  #pragma unroll
  for (int q=0;q<4;q++){ A2[q]=0.f;B2[q]=0.f;W2[q]=0.f;E2[q]=0.f;I2[q]=0;
                         As2[q]=0.f;Bs2[q]=0.f;Ws2[q]=0.f;Es2[q]=0.f;Is2[q]=0; }
  int c2max=0, smax=0;
  {
    int r=0, cnt=0;
    if (L2a){
      for (int e=0;e<32;e++){
        if (mask_at(a.mk2,md2,e*32+j2)!=0.f){
          if ((r&7)==sub && cnt<4){
            const int idx=e*32+j2;
            const float s=a.sg2[idx];
            A2[cnt]=-s*LOG2E; B2[cnt]=s*a.mu2[idx]*LOG2E;
            const float wmv=a.w2[idx];
            W2[cnt]=wmv; E2[cnt]=wmv*a.er2[idx];
            I2[cnt]=e;
            cnt++;
          }
          r++;
        }
      }
    }
    c2max = wave_max(cnt);
    r=0; cnt=0;
    if (L2a){
      for (int e=0;e<32;e++){
        if (mask_at(a.smk2,mds2,e*32+j2)!=0.f){
          if ((r&7)==sub && cnt<4){
            const int idx=e*32+j2;
            const float s=a.ssg2[idx];
            float Aq=-s*LOG2E, Bq=s*a.smu2[idx]*LOG2E;
            const float wi=a.ow1[e]*a.iw2[e];
            const float ci=fmaf(a.ob1[e],a.iw2[e],a.ib2[e]);
            Bq=fmaf(Aq,ci,Bq); Aq*=wi;
            As2[cnt]=Aq; Bs2[cnt]=Bq;
            const float wmv=a.sw2[idx];
            Ws2[cnt]=wmv; Es2[cnt]=wmv*a.ser2[idx];
            Is2[cnt]=e;
            cnt++;
          }
          r++;
        }
      }
    }
    smax = wave_max(cnt);
  }

  // per-lane neuron params
  const float cmt1=a.cm1[j1]*6.f, gl1=a.g1[j1], gv1=gl1*a.vl1[j1];
  const float cmt2=a.cm2[j2]*6.f, gl2=a.g2[j2], gv2=gl2*a.vl2[j2];

  float v1=0.f, v2=0.f;
  float bn1=0.f, bdb1=1.f, bn2=0.f, bdb2=1.f;
  float2 cur = pre[((size_t)(b<<10))*64 + j1];
  float2 nxt = make_float2(0.f,0.f);
  int p=0;

  __syncthreads();   // zeros + setup visible

  #pragma unroll 1
  for (int t=0;t<1026;t++){
    #pragma unroll
    for (int k=0;k<6;k++){
      const float* __restrict__ vb1 = v1u[p];
      // ---------------- L1 ----------------
      if (t<1024){
        if (k==0){
          bn1 = gv1 + cur.x;
          bdb1 = cmt1 + gl1 + cur.y + 1e-8f;
          if (t+1<1024) nxt = pre[((size_t)((b<<10)+t+1))*64 + j1];
        }
        float sn0=0.f,sn1=0.f,sd0=0.f,sd1=0.f;
        #pragma unroll
        for (int q=0;q<4;q++){
          const float vv=vb1[I[q]];
          const float z=fmaf(A[q],vv,B[q]);
          const float sg=frcp(1.f+fexp2(z));
          if (q&1){ sd1=fmaf(W[q],sg,sd1); sn1=fmaf(E[q],sg,sn1); }
          else    { sd0=fmaf(W[q],sg,sd0); sn0=fmaf(E[q],sg,sn0); }
        }
        if (c1max>4){
          #pragma unroll
          for (int q=4;q<8;q++){
            if (q<c1max){
              const float vv=vb1[I[q]];
              const float z=fmaf(A[q],vv,B[q]);
              const float sg=frcp(1.f+fexp2(z));
              sd0=fmaf(W[q],sg,sd0); sn0=fmaf(E[q],sg,sn0);
            }
          }
        }
        float sn=sn0+sn1, sd=sd0+sd1;
        sn += __shfl_xor(sn,1); sd += __shfl_xor(sd,1);
        sn += __shfl_xor(sn,2); sd += __shfl_xor(sd,2);
        sn += __shfl_xor(sn,4); sd += __shfl_xor(sd,4);
        v1 = (fmaf(cmt1,v1,bn1)+sn) * frcp(bdb1+sd);
        v1u[p^1][j1]=v1;                      // 8 lanes, same value
        if (k==5) v1fin[j1]=v1;
        if (k==5) cur=nxt;
      }
      // ---------------- L2 (lanes 0-31) ----------------
      if (L2a){
        const float* __restrict__ vb2 = v2u[p];
        if (k==0){
          if (t>=2){                           // unfold 5 of step t-2, OLD bn2
            float sn=0.f, sd=0.f;
            #pragma unroll
            for (int q=0;q<2;q++){
              const float vv=vb2[I2[q]];
              const float z=fmaf(A2[q],vv,B2[q]);
              const float sg=frcp(1.f+fexp2(z));
              sd=fmaf(W2[q],sg,sd); sn=fmaf(E2[q],sg,sn);
            }
            if (c2max>2){
              #pragma unroll
              for (int q=2;q<4;q++){
                if (q<c2max){
                  const float vv=vb2[I2[q]];
                  const float z=fmaf(A2[q],vv,B2[q]);
                  const float sg=frcp(1.f+fexp2(z));
                  sd=fmaf(W2[q],sg,sd); sn=fmaf(E2[q],sg,sn);
                }
              }
            }
            sn += __shfl_xor(sn,1); sd += __shfl_xor(sd,1);
            sn += __shfl_xor(sn,2); sd += __shfl_xor(sd,2);
            sn += __shfl_xor(sn,4); sd += __shfl_xor(sd,4);
            v2 = (fmaf(cmt2,v2,bn2)+sn) * frcp(bdb2+sd);
          }
          if (t>=1 && t<=1024){                // sensory for step t-1 -> NEW bn2
            float ssn=0.f, ssd=0.f;
            #pragma unroll
            for (int q=0;q<2;q++){
              const float vv=v1fin[Is2[q]];
              const float z=fmaf(As2[q],vv,Bs2[q]);
              const float sg=frcp(1.f+fexp2(z));
              ssd=fmaf(Ws2[q],sg,ssd); ssn=fmaf(Es2[q],sg,ssn);
            }
            if (smax>2){
              #pragma unroll
              for (int q=2;q<4;q++){
                if (q<smax){
                  const float vv=v1fin[Is2[q]];
                  const float z=fmaf(As2[q],vv,Bs2[q]);
                  const float sg=frcp(1.f+fexp2(z));
                  ssd=fmaf(Ws2[q],sg,ssd); ssn=fmaf(Es2[q],sg,ssn);
                }
              }
            }
            ssn += __shfl_xor(ssn,1); ssd += __shfl_xor(ssd,1);
            ssn += __shfl_xor(ssn,2); ssd += __shfl_xor(ssd,2);
            ssn += __shfl_xor(ssn,4); ssd += __shfl_xor(ssd,4);
            bn2 = gv2 + ssn;
            bdb2 = cmt2 + gl2 + ssd + 1e-8f;
          }
        } else if (t>=1 && t<=1024){           // unfold k-1 of step t-1
          float sn=0.f, sd=0.f;
          #pragma unroll
          for (int q=0;q<2;q++){
            const float vv=vb2[I2[q]];
            const float z=fmaf(A2[q],vv,B2[q]);
            const float sg=frcp(1.f+fexp2(z));
            sd=fmaf(W2[q],sg,sd); sn=fmaf(E2[q],sg,sn);
          }
          if (c2max>2){
            #pragma unroll
            for (int q=2;q<4;q++){
              if (q<c2max){
                const float vv=vb2[I2[q]];
                const float z=fmaf(A2[q],vv,B2[q]);
                const float sg=frcp(1.f+fexp2(z));
                sd=fmaf(W2[q],sg,sd); sn=fmaf(E2[q],sg,sn);
              }
            }
          }
          sn += __shfl_xor(sn,1); sd += __shfl_xor(sd,1);
          sn += __shfl_xor(sn,2); sd += __shfl_xor(sd,2);
          sn += __shfl_xor(sn,4); sd += __shfl_xor(sd,4);
          v2 = (fmaf(cmt2,v2,bn2)+sn) * frcp(bdb2+sd);
        }
        v2u[p^1][j2]=v2;                       // always (write-through keeps buffer fresh)
      }
      __syncthreads();
      p ^= 1;
    }
  }

  if (w==0 && l<16){
    float o = fmaf(v2u[p][l], a.ow2[l], a.ob2[l]) * a.fcw[l];
    o += __shfl_xor(o,1); o += __shfl_xor(o,2); o += __shfl_xor(o,4); o += __shfl_xor(o,8);
    if (l==0){
      const float z = o + a.fcb[0];
      a.out[b] = frcp(1.f + fexp2(-z*LOG2E));
    }
  }
}

// ================= fallback: fused kernel (verified) =================
__global__ __launch_bounds__(256,1)
void ltc_fused(LtcArgs a)
{
  const int b=blockIdx.x, tid=threadIdx.x;
  __shared__ __align__(16) float xs[8192];
  __shared__ __align__(16) float v1s[2][64];
  __shared__ __align__(16) float v2s[2][32];
  __shared__ __align__(16) float u1s[8][32];
  __shared__ float cwts[184];
  __shared__ int cnt[8];

  {
    const float4* xg=(const float4*)(a.x + (size_t)b*8192);
    float4* xd=(float4*)xs;
    #pragma unroll
    for (int k=0;k<8;k++) xd[tid+256*k]=xg[tid+256*k];
  }
  if (tid<8) cnt[tid]=0;
  if (tid<64){ v1s[0][tid]=0.f; v1s[1][tid]=0.f; }
  if (tid<32){ v2s[0][tid]=0.f; v2s[1][tid]=0.f; }
  if (tid<12) cwts[tid]=a.c1w[tid];
  else if (tid<16)  cwts[tid]=a.c1b[tid-12];
  else if (tid<112) cwts[tid]=a.c2w[tid-16];
  else if (tid<120) cwts[tid]=a.c2b[tid-112];
  else if (tid<152) cwts[tid]=a.iw1[tid-120];
  else if (tid<184) cwts[tid]=a.ib1[tid-152];
  __syncthreads();

  scan_mask(a.mk1, 4096, tid, &cnt[0], &cnt[1]);
  scan_mask(a.smk1,2048, tid, &cnt[2], &cnt[3]);
  scan_mask(a.mk2, 1024, tid, &cnt[4], &cnt[5]);
  scan_mask(a.smk2,1024, tid, &cnt[6], &cnt[7]);
  __syncthreads();
  const int md1 =decide_mode(cnt[0],cnt[1],4096);
  const int mds1=decide_mode(cnt[2],cnt[3],2048);
  const int md2 =decide_mode(cnt[4],cnt[5],1024);
  const int mds2=decide_mode(cnt[6],cnt[7],1024);

  const int j1=tid>>2, ig1=tid&3;
  float Au[16],Bu[16],Wu[16],Eu[16];
  #pragma unroll
  for (int e=0;e<16;e++){
    const int i=16*ig1+e, idx=i*64+j1;
    const float s=a.sg1[idx];
    Au[e]=-s*LOG2E; Bu[e]=s*a.mu1[idx]*LOG2E;
    const float wm=a.w1[idx]*mask_at(a.mk1,md1,idx);
    Wu[e]=wm; Eu[e]=wm*a.er1[idx];
  }
  float As[8],Bs[8],Ws[8],Es[8];
  #pragma unroll
  for (int e=0;e<8;e++){
    const int i=8*ig1+e, idx=i*64+j1;
    const float s=a.ssg1[idx];
    As[e]=-s*LOG2E; Bs[e]=s*a.smu1[idx]*LOG2E;
    const float wm=a.sw1[idx]*mask_at(a.smk1,mds1,idx);
    Ws[e]=wm; Es[e]=wm*a.ser1[idx];
  }
  const float cmt1=a.cm1[j1]*6.f, gl1=a.g1[j1], gv1=gl1*a.vl1[j1];

  const int j2=tid>>3, ig2=tid&7;
  float A2[4],B2[4],W2[4],E2[4],A2s[4],B2s[4],W2s[4],E2s[4],Wi2[4],Ci2[4];
  #pragma unroll
  for (int e=0;e<4;e++){
    const int i=4*ig2+e, idx=i*32+j2;
    { const float s=a.sg2[idx];
      A2[e]=-s*LOG2E; B2[e]=s*a.mu2[idx]*LOG2E;
      const float wm=a.w2[idx]*mask_at(a.mk2,md2,idx);
      W2[e]=wm; E2[e]=wm*a.er2[idx]; }
    { const float s=a.ssg2[idx];
      A2s[e]=-s*LOG2E; B2s[e]=s*a.smu2[idx]*LOG2E;
      const float wm=a.sw2[idx]*mask_at(a.smk2,mds2,idx);
      W2s[e]=wm; E2s[e]=wm*a.ser2[idx]; }
    Wi2[e]=a.ow1[i]*a.iw2[i];
    Ci2[e]=fmaf(a.ob1[i],a.iw2[i],a.ib2[i]);
  }
  const float cmt2=a.cm2[j2]*6.f, gl2=a.g2[j2], gv2=gl2*a.vl2[j2];

  float vj1=0.f, vj2=0.f;
  int p1x=0, p2x=0;
  const int cf=tid&31, cc=cf>>2, cwp=cf&3, ctc=tid>>5;

  for (int t=0;t<1024;t++){
    if ((t&7)==0){
      const float* xr = &xs[(t+ctc)*8];
      float acc = cwts[112+cc];
      #pragma unroll
      for (int ci=0;ci<4;ci++){
        const float k10=cwts[ci*3], k11=cwts[ci*3+1], k12=cwts[ci*3+2], bb=cwts[12+ci];
        #pragma unroll
        for (int kk=0;kk<3;kk++){
          const int p=cwp+kk;
          float h = fmaf(k10,xr[p], fmaf(k11,xr[p+1], fmaf(k12,xr[p+2], bb)));
          h = fmaxf(h,0.f);
          acc = fmaf(cwts[16+(cc*4+ci)*3+kk], h, acc);
        }
      }
      u1s[ctc][cf] = fmaf(acc, cwts[120+cf], cwts[152+cf]);
      __syncthreads();
    }

    float wns=0.f, wds=0.f;
    {
      const float4* uv4=(const float4*)&u1s[t&7][8*ig1];
      float4 qa=uv4[0], qb=uv4[1];
      float uvv[8]={qa.x,qa.y,qa.z,qa.w,qb.x,qb.y,qb.z,qb.w};
      #pragma unroll
      for (int e=0;e<8;e++){
        float z=fmaf(As[e],uvv[e],Bs[e]);
        float sg=frcp(1.f+fexp2(z));
        wds=fmaf(Ws[e],sg,wds);
        wns=fmaf(Es[e],sg,wns);
      }
      wns += __shfl_xor(wns,1); wns += __shfl_xor(wns,2);
      wds += __shfl_xor(wds,1); wds += __shfl_xor(wds,2);
    }
    const float bn1 = gv1 + wns;
    const float bd1 = cmt1 + gl1 + wds + 1e-8f;

    #pragma unroll
    for (int k=0;k<6;k++){
      const float4* vv4=(const float4*)&v1s[p1x][16*ig1];
      float4 q0=vv4[0], q1=vv4[1], q2=vv4[2], q3=vv4[3];
      float vi[16]={q0.x,q0.y,q0.z,q0.w,q1.x,q1.y,q1.z,q1.w,
                    q2.x,q2.y,q2.z,q2.w,q3.x,q3.y,q3.z,q3.w};
      float sn=0.f, sd=0.f;
      #pragma unroll
      for (int e=0;e<16;e++){
        float z=fmaf(Au[e],vi[e],Bu[e]);
        float sg=frcp(1.f+fexp2(z));
        sd=fmaf(Wu[e],sg,sd);
        sn=fmaf(Eu[e],sg,sn);
      }
      sn += __shfl_xor(sn,1); sn += __shfl_xor(sn,2);
      sd += __shfl_xor(sd,1); sd += __shfl_xor(sd,2);
      vj1 = (fmaf(cmt1,vj1,bn1)+sn) * frcp(bd1+sd);
      p1x ^= 1;
      if (ig1==0) v1s[p1x][j1]=vj1;
      __syncthreads();
    }

    float wns2=0.f, wds2=0.f;
    {
      const float4* vf4=(const float4*)&v1s[p1x][4*ig2];
      float4 vf=vf4[0];
      float vin[4]={vf.x,vf.y,vf.z,vf.w};
      #pragma unroll
      for (int e=0;e<4;e++){
        float u2=fmaf(vin[e],Wi2[e],Ci2[e]);
        float z=fmaf(A2s[e],u2,B2s[e]);
        float sg=frcp(1.f+fexp2(z));
        wds2=fmaf(W2s[e],sg,wds2);
        wns2=fmaf(E2s[e],sg,wns2);
      }
      wns2 += __shfl_xor(wns2,1); wns2 += __shfl_xor(wns2,2); wns2 += __shfl_xor(wns2,4);
      wds2 += __shfl_xor(wds2,1); wds2 += __shfl_xor(wds2,2); wds2 += __shfl_xor(wds2,4);
    }
    const float bn2 = gv2 + wns2;
    const float bd2 = cmt2 + gl2 + wds2 + 1e-8f;

    #pragma unroll
    for (int k=0;k<6;k++){
      const float4* vv4=(const float4*)&v2s[p2x][4*ig2];
      float4 q=vv4[0];
      float vi[4]={q.x,q.y,q.z,q.w};
      float sn=0.f, sd=0.f;
      #pragma unroll
      for (int e=0;e<4;e++){
        float z=fmaf(A2[e],vi[e],B2[e]);
        float sg=frcp(1.f+fexp2(z));
        sd=fmaf(W2[e],sg,sd);
        sn=fmaf(E2[e],sg,sn);
      }
      sn += __shfl_xor(sn,1); sn += __shfl_xor(sn,2); sn += __shfl_xor(sn,4);
      sd += __shfl_xor(sd,1); sd += __shfl_xor(sd,2); sd += __shfl_xor(sd,4);
      vj2 = (fmaf(cmt2,vj2,bn2)+sn) * frcp(bd2+sd);
      p2x ^= 1;
      if (ig2==0) v2s[p2x][j2]=vj2;
      __syncthreads();
    }
  }

  if (tid<16){
    float o = fmaf(v2s[p2x][tid], a.ow2[tid], a.ob2[tid]) * a.fcw[tid];
    o += __shfl_xor(o,1); o += __shfl_xor(o,2); o += __shfl_xor(o,4); o += __shfl_xor(o,8);
    if (tid==0){
      float z = o + a.fcb[0];
      a.out[b] = frcp(1.f + fexp2(-z*LOG2E));
    }
  }
}

extern "C" void kernel_launch(void* const* d_in, const int* in_sizes, int n_in,
                              void* d_out, int out_size, void* d_ws, size_t ws_size,
                              hipStream_t stream)
{
  (void)out_size;
  int o[41];
  for (int i=0;i<41;i++) o[i]=i;
  if (n_in>=41 && in_sizes[20]!=4096){
    for (int i=0;i<15;i++) o[5+i]=5+i;
    o[20]=37; o[21]=38;
    for (int i=0;i<15;i++) o[22+i]=20+i;
    o[37]=39; o[38]=40;
    o[39]=35; o[40]=36;
  }
  const float* F[41];
  for (int i=0;i<41;i++) F[i]=(const float*)d_in[o[i]];
  LtcArgs a;
  a.x=F[0]; a.c1w=F[1]; a.c1b=F[2]; a.c2w=F[3]; a.c2b=F[4];
  a.g1=F[5]; a.vl1=F[6]; a.cm1=F[7]; a.sg1=F[8]; a.mu1=F[9]; a.w1=F[10]; a.er1=F[11];
  a.ssg1=F[12]; a.smu1=F[13]; a.sw1=F[14]; a.ser1=F[15];
  a.iw1=F[16]; a.ib1=F[17]; a.ow1=F[18]; a.ob1=F[19];
  a.mk1=(const void*)d_in[o[20]]; a.smk1=(const void*)d_in[o[21]];
  a.g2=F[22]; a.vl2=F[23]; a.cm2=F[24]; a.sg2=F[25]; a.mu2=F[26]; a.w2=F[27]; a.er2=F[28];
  a.ssg2=F[29]; a.smu2=F[30]; a.sw2=F[31]; a.ser2=F[32];
  a.iw2=F[33]; a.ib2=F[34]; a.ow2=F[35]; a.ob2=F[36];
  a.mk2=(const void*)d_in[o[37]]; a.smk2=(const void*)d_in[o[38]];
  a.fcw=F[39]; a.fcb=F[40];
  a.out=(float*)d_out;

  const size_t need = 256 + (size_t)256*1024*64*sizeof(float2);
  if (ws_size >= need){
    int* hdr = (int*)d_ws;
    float2* pre = (float2*)((char*)d_ws + 256);
    ltc_modes<<<dim3(1),dim3(256),0,stream>>>(a.mk1,a.smk1,a.mk2,a.smk2,hdr);
    ltc_pre<<<dim3(256,16),dim3(256),0,stream>>>(a,hdr,pre);
    ltc_scan<<<dim3(256),dim3(512),0,stream>>>(a,pre,hdr);
  } else {
    ltc_fused<<<dim3(256),dim3(256),0,stream>>>(a);
  }
}

// Round 7
// 4846.885 us; speedup vs baseline: 1.0711x; 1.0711x over previous
//
#include <hip/hip_runtime.h>
#include <stdint.h>

#define LOG2E 1.44269504088896340736f

struct LtcArgs {
  const float *x, *c1w, *c1b, *c2w, *c2b;
  const float *g1,*vl1,*cm1,*sg1,*mu1,*w1,*er1,*ssg1,*smu1,*sw1,*ser1,*iw1,*ib1,*ow1,*ob1;
  const void  *mk1,*smk1;
  const float *g2,*vl2,*cm2,*sg2,*mu2,*w2,*er2,*ssg2,*smu2,*sw2,*ser2,*iw2,*ib2,*ow2,*ob2;
  const void  *mk2,*smk2;
  const float *fcw,*fcb;
  float *out;
};

__device__ __forceinline__ float fexp2(float v){ return __builtin_amdgcn_exp2f(v); }
__device__ __forceinline__ float frcp (float v){ return __builtin_amdgcn_rcpf(v); }
// per-lane variable gather within the wave (ds_bpermute); index is PRE-SHIFTED byte addr
__device__ __forceinline__ float gatherb(float v, int byteLane){
  return __int_as_float(__builtin_amdgcn_ds_bpermute(byteLane, __float_as_int(v)));
}
__device__ __forceinline__ int wave_max(int v){
  #pragma unroll
  for (int s=1;s<64;s<<=1){ int o=__shfl_xor(v,s); v = o>v ? o : v; }
  return __builtin_amdgcn_readfirstlane(v);
}

// ---- mask dtype detection (verified: absmax 0) ----
__device__ __forceinline__ void scan_mask(const void* p, int n, int tid, int* cge2, int* cone){
  const uint8_t* bp = (const uint8_t*)p;
  int g=0,o=0;
  for (int k=tid;k<n;k+=256){ uint8_t v=bp[k]; g += (v>=2); o += (v==1); }
  if (g) atomicAdd(cge2,g);
  if (o) atomicAdd(cone,o);
}
__device__ __forceinline__ int decide_mode(int ge2,int one,int n){
  if (ge2 > (n>>4)) return 2;
  if (one > (n>>2)) return 0;
  return 1;
}
__device__ __forceinline__ float mask_at(const void* p,int mode,int idx){
  if (mode==2) return ((const float*)p)[idx]!=0.f ? 1.f:0.f;
  if (mode==1) return ((const int*)p)[idx]!=0 ? 1.f:0.f;
  return ((const uint8_t*)p)[idx]!=0 ? 1.f:0.f;
}

// ================= kernel 0: mask modes -> hdr =================
__global__ void ltc_modes(const void* mk1,const void* smk1,const void* mk2,const void* smk2,int* hdr){
  __shared__ int cnt[8];
  const int tid=threadIdx.x;
  if (tid<8) cnt[tid]=0;
  __syncthreads();
  scan_mask(mk1, 4096, tid, &cnt[0], &cnt[1]);
  scan_mask(smk1,2048, tid, &cnt[2], &cnt[3]);
  scan_mask(mk2, 1024, tid, &cnt[4], &cnt[5]);
  scan_mask(smk2,1024, tid, &cnt[6], &cnt[7]);
  __syncthreads();
  if (tid==0){
    hdr[0]=decide_mode(cnt[0],cnt[1],4096);
    hdr[1]=decide_mode(cnt[2],cnt[3],2048);
    hdr[2]=decide_mode(cnt[4],cnt[5],1024);
    hdr[3]=decide_mode(cnt[6],cnt[7],1024);
  }
}

// ================= kernel 1: precompute conv + L1 synapse sums =================
__global__ __launch_bounds__(256,2)
void ltc_pre(LtcArgs a, const int* __restrict__ hdr, float2* __restrict__ pre)
{
  const int b=blockIdx.x, tb=blockIdx.y*64, tid=threadIdx.x;
  const int mds1=hdr[1];
  __shared__ float us[4][32];

  const int j = tid&63;
  float As[32],Bs[32],Ws[32],Es[32];
  #pragma unroll
  for (int e=0;e<32;e++){
    const int idx=e*64+j;
    const float s=a.ssg1[idx];
    As[e]=-s*LOG2E; Bs[e]=s*a.smu1[idx]*LOG2E;
    const float wm=a.sw1[idx]*mask_at(a.smk1,mds1,idx);
    Ws[e]=wm; Es[e]=wm*a.ser1[idx];
  }
  const int th=tid>>5, f=tid&31, cc=f>>2, cwp=f&3;
  float k1[12],b1[4],k2[12],cb2=0.f,wi=0.f,bi=0.f;
  if (tid<128){
    #pragma unroll
    for (int q=0;q<12;q++) k1[q]=a.c1w[q];
    #pragma unroll
    for (int q=0;q<4;q++)  b1[q]=a.c1b[q];
    #pragma unroll
    for (int q=0;q<12;q++) k2[q]=a.c2w[cc*12+q];
    cb2=a.c2b[cc]; wi=a.iw1[f]; bi=a.ib1[f];
  }

  for (int tt=0; tt<64; tt+=4){
    if (tid<128){
      const int t=tb+tt+th;
      const float4* xg=(const float4*)(a.x + ((size_t)b*1024 + t)*8);
      float4 xa=xg[0], xb=xg[1];
      float xr[8]={xa.x,xa.y,xa.z,xa.w,xb.x,xb.y,xb.z,xb.w};
      float acc=cb2;
      #pragma unroll
      for (int ci=0;ci<4;ci++){
        const float q0=k1[ci*3],q1=k1[ci*3+1],q2=k1[ci*3+2],bb=b1[ci];
        #pragma unroll
        for (int kk=0;kk<3;kk++){
          const int p=cwp+kk;
          float h=fmaf(q0,xr[p],fmaf(q1,xr[p+1],fmaf(q2,xr[p+2],bb)));
          h=fmaxf(h,0.f);
          acc=fmaf(k2[ci*3+kk],h,acc);
        }
      }
      us[th][f]=fmaf(acc,wi,bi);
    }
    __syncthreads();
    {
      const int t4=tid>>6;
      float wns=0.f,wds=0.f;
      #pragma unroll
      for (int e=0;e<32;e++){
        const float u=us[t4][e];
        const float z=fmaf(As[e],u,Bs[e]);
        const float sg=frcp(1.f+fexp2(z));
        wds=fmaf(Ws[e],sg,wds);
        wns=fmaf(Es[e],sg,wns);
      }
      pre[((size_t)((b<<10)+tb+tt+t4))*64 + j] = make_float2(wns,wds);
    }
    __syncthreads();
  }
}

// ================= kernel 2: sequential scan, symmetric merged 4-wave =================
// 256 blocks x 256 thr (4 waves = 1/SIMD). Every wave does BOTH layers (R0's
// L2-only waves issued ~half of L1 waves -> wasted SIMD capacity + barrier
// skew). Wave w: L1 lane=neuron l, ranks==w (mod 4), 11 uncond slots + guarded
// tail to 16 (R0-proven); L2 lane owns v2[l&31], c=(w<<1)|(l>>5) in [0,8),
// ranks==c (mod 8), 4 slots exact. All gathers are bpermute-from-register
// (R6 lesson: LDS-gather + shfl-tree chains are slower). Sensory gathers v1
// register at k==0 pre-barrier (= v1fin(t-1) before updates) -> v1buf LDS
// round-trip eliminated. L2 lags exactly 1 timestep, unfolds aligned to
// segments. Partials double-buffered by k&1; ONE barrier/segment (6150 total).
// R3: no LDS float atomics. R4: no serial reducer. R6: no LDS v-gather/shfl.
__global__ __launch_bounds__(256,1)
void ltc_scan(LtcArgs a, const float2* __restrict__ pre, const int* __restrict__ hdr)
{
  const int b=blockIdx.x, tid=threadIdx.x;
  const int w=tid>>6, l=tid&63;
  const int j2=l&31;
  const int c=(w<<1)|(l>>5);           // L2 partial slot in [0,8)

  __shared__ float2 p1[2][4][64];      // L1 partials (sn,sd), dbuf by k&1
  __shared__ float2 p2[2][8][32];      // L2 unfold partials
  __shared__ float2 psb[8][32];        // L2 sensory partials (k==0 only)

  const int md1=hdr[0], md2=hdr[2], mds2=hdr[3];

  // ---- L1 slots: ranks == w (mod 4), 11 uncond + tail to 16 ----
  float A[16],B[16],W[16],E[16]; int I[16];
  #pragma unroll
  for (int q=0;q<16;q++){ A[q]=0.f;B[q]=0.f;W[q]=0.f;E[q]=0.f;I[q]=0; }
  int c1max=0;
  {
    unsigned long long mm=0ull;
    for (int e=0;e<64;e++)
      if (mask_at(a.mk1,md1,e*64+l)!=0.f) mm |= (1ull<<e);
    int r=0, cnt=0;
    while (mm){
      const int e=(int)__builtin_ctzll(mm); mm&=mm-1;
      if ((r&3)==w && cnt<16){
        const int idx=e*64+l;
        const float s=a.sg1[idx];
        A[cnt]=-s*LOG2E; B[cnt]=s*a.mu1[idx]*LOG2E;
        const float wmv=a.w1[idx];
        W[cnt]=wmv; E[cnt]=wmv*a.er1[idx];
        I[cnt]=e<<2;                   // pre-shifted bpermute byte index
        cnt++;
      }
      r++;
    }
    c1max = wave_max(cnt);
  }

  // ---- L2 slots: ranks == c (mod 8) over 32 inputs; 4 slots exact ----
  float A2[4],B2[4],W2[4],E2[4]; int I2[4];
  float As2[4],Bs2[4],Ws2[4],Es2[4]; int Is2[4];
  #pragma unroll
  for (int q=0;q<4;q++){ A2[q]=0.f;B2[q]=0.f;W2[q]=0.f;E2[q]=0.f;I2[q]=0;
                         As2[q]=0.f;Bs2[q]=0.f;Ws2[q]=0.f;Es2[q]=0.f;Is2[q]=0; }
  { // main synapse (mk2)
    unsigned mm=0u;
    for (int e=0;e<32;e++)
      if (mask_at(a.mk2,md2,e*32+j2)!=0.f) mm |= (1u<<e);
    int r=0, cnt=0;
    while (mm){
      const int e=(int)__builtin_ctz(mm); mm&=mm-1;
      if ((r&7)==c && cnt<4){
        const int idx=e*32+j2;
        const float s=a.sg2[idx];
        A2[cnt]=-s*LOG2E; B2[cnt]=s*a.mu2[idx]*LOG2E;
        const float wmv=a.w2[idx];
        W2[cnt]=wmv; E2[cnt]=wmv*a.er2[idx];
        I2[cnt]=e<<2;                  // bpermute byte index (lane e holds v2[e])
        cnt++;
      }
      r++;
    }
  }
  { // sensory synapse (smk2), input-affine folded; gathers v1 REGISTER
    unsigned mm=0u;
    for (int e=0;e<32;e++)
      if (mask_at(a.smk2,mds2,e*32+j2)!=0.f) mm |= (1u<<e);
    int r=0, cnt=0;
    while (mm){
      const int e=(int)__builtin_ctz(mm); mm&=mm-1;
      if ((r&7)==c && cnt<4){
        const int idx=e*32+j2;
        const float s=a.ssg2[idx];
        float Aq=-s*LOG2E, Bq=s*a.smu2[idx]*LOG2E;
        const float wi=a.ow1[e]*a.iw2[e];
        const float ci=fmaf(a.ob1[e],a.iw2[e],a.ib2[e]);
        Bq=fmaf(Aq,ci,Bq); Aq*=wi;
        As2[cnt]=Aq; Bs2[cnt]=Bq;
        const float wmv=a.sw2[idx];
        Ws2[cnt]=wmv; Es2[cnt]=wmv*a.ser2[idx];
        Is2[cnt]=e<<2;                 // bpermute byte index into v1 register
        cnt++;
      }
      r++;
    }
  }

  const float cmt1=a.cm1[l]*6.f,  gl1=a.g1[l],  gv1=gl1*a.vl1[l];
  const float cmt2=a.cm2[j2]*6.f, gl2=a.g2[j2], gv2=gl2*a.vl2[j2];

  float v1=0.f, v2=0.f;
  float bn1=0.f, bdb1=1.f, bn2=0.f, bdb2=1.f;
  float2 cur = pre[((size_t)(b<<10))*64 + l];
  float2 nxt = make_float2(0.f,0.f);

  __syncthreads();

  #pragma unroll 1
  for (int t=0;t<1025;t++){
    const bool l1act = (t<1024);
    const bool l2act = (t>=1);
    #pragma unroll
    for (int k=0;k<6;k++){
      const int buf = k&1;
      // ---------- pre-barrier: slot partials ----------
      if (l1act){
        float sn0=0.f,sn1=0.f,sd0=0.f,sd1=0.f;
        #pragma unroll
        for (int q=0;q<11;q++){            // branch-free common path (R0-proven)
          const float vv=gatherb(v1, I[q]);
          const float z=fmaf(A[q],vv,B[q]);
          const float sg=frcp(1.f+fexp2(z));
          if (q&1){ sd1=fmaf(W[q],sg,sd1); sn1=fmaf(E[q],sg,sn1); }
          else    { sd0=fmaf(W[q],sg,sd0); sn0=fmaf(E[q],sg,sn0); }
        }
        if (c1max>11){                     // rare tail (wave-uniform scalar branch)
          #pragma unroll
          for (int q=11;q<16;q++){
            if (q<c1max){
              const float vv=gatherb(v1, I[q]);
              const float z=fmaf(A[q],vv,B[q]);
              const float sg=frcp(1.f+fexp2(z));
              sd0=fmaf(W[q],sg,sd0); sn0=fmaf(E[q],sg,sn0);
            }
          }
        }
        p1[buf][w][l]=make_float2(sn0+sn1, sd0+sd1);
      }
      if (l2act){
        float sn=0.f, sd=0.f;
        #pragma unroll
        for (int q=0;q<4;q++){             // branch-free, exact
          const float vv=gatherb(v2, I2[q]);
          const float z=fmaf(A2[q],vv,B2[q]);
          const float sg=frcp(1.f+fexp2(z));
          sd=fmaf(W2[q],sg,sd);
          sn=fmaf(E2[q],sg,sn);
        }
        p2[buf][c][j2]=make_float2(sn,sd);
        if (k==0){                         // sensory from v1 register (= v1fin(t-1))
          float ssn=0.f, ssd=0.f;
          #pragma unroll
          for (int q=0;q<4;q++){
            const float vb=gatherb(v1, Is2[q]);
            const float z=fmaf(As2[q],vb,Bs2[q]);
            const float sg=frcp(1.f+fexp2(z));
            ssd=fmaf(Ws2[q],sg,ssd);
            ssn=fmaf(Es2[q],sg,ssn);
          }
          psb[c][j2]=make_float2(ssn,ssd);
        }
      }
      __syncthreads();
      // ---------- post-barrier: replicated tree readback + updates ----------
      if (l1act){
        if (k==0){
          bn1 = gv1 + cur.x;
          bdb1 = cmt1 + gl1 + cur.y + 1e-8f;
          if (t+1<1024) nxt = pre[((size_t)((b<<10)+t+1))*64 + l];
        }
        const float2 q0=p1[buf][0][l], q1=p1[buf][1][l], q2=p1[buf][2][l], q3=p1[buf][3][l];
        const float sn = (q0.x+q1.x)+(q2.x+q3.x);
        const float sd = (q0.y+q1.y)+(q2.y+q3.y);
        v1 = (fmaf(cmt1,v1,bn1)+sn) * frcp(bdb1+sd);
        if (k==5) cur=nxt;
      }
      if (l2act){
        if (k==0){
          float2 s0=psb[0][j2], s1=psb[1][j2], s2=psb[2][j2], s3=psb[3][j2];
          float2 s4=psb[4][j2], s5=psb[5][j2], s6=psb[6][j2], s7=psb[7][j2];
          const float wns=((s0.x+s1.x)+(s2.x+s3.x))+((s4.x+s5.x)+(s6.x+s7.x));
          const float wds=((s0.y+s1.y)+(s2.y+s3.y))+((s4.y+s5.y)+(s6.y+s7.y));
          bn2 = gv2 + wns;
          bdb2 = cmt2 + gl2 + wds + 1e-8f;
        }
        float2 s0=p2[buf][0][j2], s1=p2[buf][1][j2], s2=p2[buf][2][j2], s3=p2[buf][3][j2];
        float2 s4=p2[buf][4][j2], s5=p2[buf][5][j2], s6=p2[buf][6][j2], s7=p2[buf][7][j2];
        const float sn=((s0.x+s1.x)+(s2.x+s3.x))+((s4.x+s5.x)+(s6.x+s7.x));
        const float sd=((s0.y+s1.y)+(s2.y+s3.y))+((s4.y+s5.y)+(s6.y+s7.y));
        v2 = (fmaf(cmt2,v2,bn2)+sn) * frcp(bdb2+sd);   // unfold k of step t-1
      }
    }
  }

  if (w==0 && l<16){
    float o = fmaf(v2, a.ow2[l], a.ob2[l]) * a.fcw[l];
    o += __shfl_xor(o,1); o += __shfl_xor(o,2); o += __shfl_xor(o,4); o += __shfl_xor(o,8);
    if (l==0){
      const float z = o + a.fcb[0];
      a.out[b] = frcp(1.f + fexp2(-z*LOG2E));
    }
  }
}

// ================= fallback: fused kernel (verified) =================
__global__ __launch_bounds__(256,1)
void ltc_fused(LtcArgs a)
{
  const int b=blockIdx.x, tid=threadIdx.x;
  __shared__ __align__(16) float xs[8192];
  __shared__ __align__(16) float v1s[2][64];
  __shared__ __align__(16) float v2s[2][32];
  __shared__ __align__(16) float u1s[8][32];
  __shared__ float cwts[184];
  __shared__ int cnt[8];

  {
    const float4* xg=(const float4*)(a.x + (size_t)b*8192);
    float4* xd=(float4*)xs;
    #pragma unroll
    for (int k=0;k<8;k++) xd[tid+256*k]=xg[tid+256*k];
  }
  if (tid<8) cnt[tid]=0;
  if (tid<64){ v1s[0][tid]=0.f; v1s[1][tid]=0.f; }
  if (tid<32){ v2s[0][tid]=0.f; v2s[1][tid]=0.f; }
  if (tid<12) cwts[tid]=a.c1w[tid];
  else if (tid<16)  cwts[tid]=a.c1b[tid-12];
  else if (tid<112) cwts[tid]=a.c2w[tid-16];
  else if (tid<120) cwts[tid]=a.c2b[tid-112];
  else if (tid<152) cwts[tid]=a.iw1[tid-120];
  else if (tid<184) cwts[tid]=a.ib1[tid-152];
  __syncthreads();

  scan_mask(a.mk1, 4096, tid, &cnt[0], &cnt[1]);
  scan_mask(a.smk1,2048, tid, &cnt[2], &cnt[3]);
  scan_mask(a.mk2, 1024, tid, &cnt[4], &cnt[5]);
  scan_mask(a.smk2,1024, tid, &cnt[6], &cnt[7]);
  __syncthreads();
  const int md1 =decide_mode(cnt[0],cnt[1],4096);
  const int mds1=decide_mode(cnt[2],cnt[3],2048);
  const int md2 =decide_mode(cnt[4],cnt[5],1024);
  const int mds2=decide_mode(cnt[6],cnt[7],1024);

  const int j1=tid>>2, ig1=tid&3;
  float Au[16],Bu[16],Wu[16],Eu[16];
  #pragma unroll
  for (int e=0;e<16;e++){
    const int i=16*ig1+e, idx=i*64+j1;
    const float s=a.sg1[idx];
    Au[e]=-s*LOG2E; Bu[e]=s*a.mu1[idx]*LOG2E;
    const float wm=a.w1[idx]*mask_at(a.mk1,md1,idx);
    Wu[e]=wm; Eu[e]=wm*a.er1[idx];
  }
  float As[8],Bs[8],Ws[8],Es[8];
  #pragma unroll
  for (int e=0;e<8;e++){
    const int i=8*ig1+e, idx=i*64+j1;
    const float s=a.ssg1[idx];
    As[e]=-s*LOG2E; Bs[e]=s*a.smu1[idx]*LOG2E;
    const float wm=a.sw1[idx]*mask_at(a.smk1,mds1,idx);
    Ws[e]=wm; Es[e]=wm*a.ser1[idx];
  }
  const float cmt1=a.cm1[j1]*6.f, gl1=a.g1[j1], gv1=gl1*a.vl1[j1];

  const int j2=tid>>3, ig2=tid&7;
  float A2[4],B2[4],W2[4],E2[4],A2s[4],B2s[4],W2s[4],E2s[4],Wi2[4],Ci2[4];
  #pragma unroll
  for (int e=0;e<4;e++){
    const int i=4*ig2+e, idx=i*32+j2;
    { const float s=a.sg2[idx];
      A2[e]=-s*LOG2E; B2[e]=s*a.mu2[idx]*LOG2E;
      const float wm=a.w2[idx]*mask_at(a.mk2,md2,idx);
      W2[e]=wm; E2[e]=wm*a.er2[idx]; }
    { const float s=a.ssg2[idx];
      A2s[e]=-s*LOG2E; B2s[e]=s*a.smu2[idx]*LOG2E;
      const float wm=a.sw2[idx]*mask_at(a.smk2,mds2,idx);
      W2s[e]=wm; E2s[e]=wm*a.ser2[idx]; }
    Wi2[e]=a.ow1[i]*a.iw2[i];
    Ci2[e]=fmaf(a.ob1[i],a.iw2[i],a.ib2[i]);
  }
  const float cmt2=a.cm2[j2]*6.f, gl2=a.g2[j2], gv2=gl2*a.vl2[j2];

  float vj1=0.f, vj2=0.f;
  int p1x=0, p2x=0;
  const int cf=tid&31, cc=cf>>2, cwp=cf&3, ctc=tid>>5;

  for (int t=0;t<1024;t++){
    if ((t&7)==0){
      const float* xr = &xs[(t+ctc)*8];
      float acc = cwts[112+cc];
      #pragma unroll
      for (int ci=0;ci<4;ci++){
        const float k10=cwts[ci*3], k11=cwts[ci*3+1], k12=cwts[ci*3+2], bb=cwts[12+ci];
        #pragma unroll
        for (int kk=0;kk<3;kk++){
          const int p=cwp+kk;
          float h = fmaf(k10,xr[p], fmaf(k11,xr[p+1], fmaf(k12,xr[p+2], bb)));
          h = fmaxf(h,0.f);
          acc = fmaf(cwts[16+(cc*4+ci)*3+kk], h, acc);
        }
      }
      u1s[ctc][cf] = fmaf(acc, cwts[120+cf], cwts[152+cf]);
      __syncthreads();
    }

    float wns=0.f, wds=0.f;
    {
      const float4* uv4=(const float4*)&u1s[t&7][8*ig1];
      float4 qa=uv4[0], qb=uv4[1];
      float uvv[8]={qa.x,qa.y,qa.z,qa.w,qb.x,qb.y,qb.z,qb.w};
      #pragma unroll
      for (int e=0;e<8;e++){
        float z=fmaf(As[e],uvv[e],Bs[e]);
        float sg=frcp(1.f+fexp2(z));
        wds=fmaf(Ws[e],sg,wds);
        wns=fmaf(Es[e],sg,wns);
      }
      wns += __shfl_xor(wns,1); wns += __shfl_xor(wns,2);
      wds += __shfl_xor(wds,1); wds += __shfl_xor(wds,2);
    }
    const float bn1 = gv1 + wns;
    const float bd1 = cmt1 + gl1 + wds + 1e-8f;

    #pragma unroll
    for (int k=0;k<6;k++){
      const float4* vv4=(const float4*)&v1s[p1x][16*ig1];
      float4 q0=vv4[0], q1=vv4[1], q2=vv4[2], q3=vv4[3];
      float vi[16]={q0.x,q0.y,q0.z,q0.w,q1.x,q1.y,q1.z,q1.w,
                    q2.x,q2.y,q2.z,q2.w,q3.x,q3.y,q3.z,q3.w};
      float sn=0.f, sd=0.f;
      #pragma unroll
      for (int e=0;e<16;e++){
        float z=fmaf(Au[e],vi[e],Bu[e]);
        float sg=frcp(1.f+fexp2(z));
        sd=fmaf(Wu[e],sg,sd);
        sn=fmaf(Eu[e],sg,sn);
      }
      sn += __shfl_xor(sn,1); sn += __shfl_xor(sn,2);
      sd += __shfl_xor(sd,1); sd += __shfl_xor(sd,2);
      vj1 = (fmaf(cmt1,vj1,bn1)+sn) * frcp(bd1+sd);
      p1x ^= 1;
      if (ig1==0) v1s[p1x][j1]=vj1;
      __syncthreads();
    }

    float wns2=0.f, wds2=0.f;
    {
      const float4* vf4=(const float4*)&v1s[p1x][4*ig2];
      float4 vf=vf4[0];
      float vin[4]={vf.x,vf.y,vf.z,vf.w};
      #pragma unroll
      for (int e=0;e<4;e++){
        float u2=fmaf(vin[e],Wi2[e],Ci2[e]);
        float z=fmaf(A2s[e],u2,B2s[e]);
        float sg=frcp(1.f+fexp2(z));
        wds2=fmaf(W2s[e],sg,wds2);
        wns2=fmaf(E2s[e],sg,wns2);
      }
      wns2 += __shfl_xor(wns2,1); wns2 += __shfl_xor(wns2,2); wns2 += __shfl_xor(wns2,4);
      wds2 += __shfl_xor(wds2,1); wds2 += __shfl_xor(wds2,2); wds2 += __shfl_xor(wds2,4);
    }
    const float bn2 = gv2 + wns2;
    const float bd2 = cmt2 + gl2 + wds2 + 1e-8f;

    #pragma unroll
    for (int k=0;k<6;k++){
      const float4* vv4=(const float4*)&v2s[p2x][4*ig2];
      float4 q=vv4[0];
      float vi[4]={q.x,q.y,q.z,q.w};
      float sn=0.f, sd=0.f;
      #pragma unroll
      for (int e=0;e<4;e++){
        float z=fmaf(A2[e],vi[e],B2[e]);
        float sg=frcp(1.f+fexp2(z));
        sd=fmaf(W2[e],sg,sd);
        sn=fmaf(E2[e],sg,sn);
      }
      sn += __shfl_xor(sn,1); sn += __shfl_xor(sn,2); sn += __shfl_xor(sn,4);
      sd += __shfl_xor(sd,1); sd += __shfl_xor(sd,2); sd += __shfl_xor(sd,4);
      vj2 = (fmaf(cmt2,vj2,bn2)+sn) * frcp(bd2+sd);
      p2x ^= 1;
      if (ig2==0) v2s[p2x][j2]=vj2;
      __syncthreads();
    }
  }

  if (tid<16){
    float o = fmaf(v2s[p2x][tid], a.ow2[tid], a.ob2[tid]) * a.fcw[tid];
    o += __shfl_xor(o,1); o += __shfl_xor(o,2); o += __shfl_xor(o,4); o += __shfl_xor(o,8);
    if (tid==0){
      float z = o + a.fcb[0];
      a.out[b] = frcp(1.f + fexp2(-z*LOG2E));
    }
  }
}

extern "C" void kernel_launch(void* const* d_in, const int* in_sizes, int n_in,
                              void* d_out, int out_size, void* d_ws, size_t ws_size,
                              hipStream_t stream)
{
  (void)out_size;
  int o[41];
  for (int i=0;i<41;i++) o[i]=i;
  if (n_in>=41 && in_sizes[20]!=4096){
    for (int i=0;i<15;i++) o[5+i]=5+i;
    o[20]=37; o[21]=38;
    for (int i=0;i<15;i++) o[22+i]=20+i;
    o[37]=39; o[38]=40;
    o[39]=35; o[40]=36;
  }
  const float* F[41];
  for (int i=0;i<41;i++) F[i]=(const float*)d_in[o[i]];
  LtcArgs a;
  a.x=F[0]; a.c1w=F[1]; a.c1b=F[2]; a.c2w=F[3]; a.c2b=F[4];
  a.g1=F[5]; a.vl1=F[6]; a.cm1=F[7]; a.sg1=F[8]; a.mu1=F[9]; a.w1=F[10]; a.er1=F[11];
  a.ssg1=F[12]; a.smu1=F[13]; a.sw1=F[14]; a.ser1=F[15];
  a.iw1=F[16]; a.ib1=F[17]; a.ow1=F[18]; a.ob1=F[19];
  a.mk1=(const void*)d_in[o[20]]; a.smk1=(const void*)d_in[o[21]];
  a.g2=F[22]; a.vl2=F[23]; a.cm2=F[24]; a.sg2=F[25]; a.mu2=F[26]; a.w2=F[27]; a.er2=F[28];
  a.ssg2=F[29]; a.smu2=F[30]; a.sw2=F[31]; a.ser2=F[32];
  a.iw2=F[33]; a.ib2=F[34]; a.ow2=F[35]; a.ob2=F[36];
  a.mk2=(const void*)d_in[o[37]]; a.smk2=(const void*)d_in[o[38]];
  a.fcw=F[39]; a.fcb=F[40];
  a.out=(float*)d_out;

  const size_t need = 256 + (size_t)256*1024*64*sizeof(float2);
  if (ws_size >= need){
    int* hdr = (int*)d_ws;
    float2* pre = (float2*)((char*)d_ws + 256);
    ltc_modes<<<dim3(1),dim3(256),0,stream>>>(a.mk1,a.smk1,a.mk2,a.smk2,hdr);
    ltc_pre<<<dim3(256,16),dim3(256),0,stream>>>(a,hdr,pre);
    ltc_scan<<<dim3(256),dim3(256),0,stream>>>(a,pre,hdr);
  } else {
    ltc_fused<<<dim3(256),dim3(256),0,stream>>>(a);
  }
}

// Round 8
// 3609.156 us; speedup vs baseline: 1.4384x; 1.3429x over previous
//
#include <hip/hip_runtime.h>
#include <stdint.h>

#define LOG2E 1.44269504088896340736f

struct LtcArgs {
  const float *x, *c1w, *c1b, *c2w, *c2b;
  const float *g1,*vl1,*cm1,*sg1,*mu1,*w1,*er1,*ssg1,*smu1,*sw1,*ser1,*iw1,*ib1,*ow1,*ob1;
  const void  *mk1,*smk1;
  const float *g2,*vl2,*cm2,*sg2,*mu2,*w2,*er2,*ssg2,*smu2,*sw2,*ser2,*iw2,*ib2,*ow2,*ob2;
  const void  *mk2,*smk2;
  const float *fcw,*fcb;
  float *out;
};

__device__ __forceinline__ float fexp2(float v){ return __builtin_amdgcn_exp2f(v); }
__device__ __forceinline__ float frcp (float v){ return __builtin_amdgcn_rcpf(v); }
// per-lane variable gather within the wave (ds_bpermute); index is PRE-SHIFTED byte addr
__device__ __forceinline__ float gatherb(float v, int byteLane){
  return __int_as_float(__builtin_amdgcn_ds_bpermute(byteLane, __float_as_int(v)));
}
__device__ __forceinline__ int wave_max(int v){
  #pragma unroll
  for (int s=1;s<64;s<<=1){ int o=__shfl_xor(v,s); v = o>v ? o : v; }
  return __builtin_amdgcn_readfirstlane(v);
}

// ---- mask dtype detection (verified: absmax 0) ----
__device__ __forceinline__ void scan_mask(const void* p, int n, int tid, int* cge2, int* cone){
  const uint8_t* bp = (const uint8_t*)p;
  int g=0,o=0;
  for (int k=tid;k<n;k+=256){ uint8_t v=bp[k]; g += (v>=2); o += (v==1); }
  if (g) atomicAdd(cge2,g);
  if (o) atomicAdd(cone,o);
}
__device__ __forceinline__ int decide_mode(int ge2,int one,int n){
  if (ge2 > (n>>4)) return 2;
  if (one > (n>>2)) return 0;
  return 1;
}
__device__ __forceinline__ float mask_at(const void* p,int mode,int idx){
  if (mode==2) return ((const float*)p)[idx]!=0.f ? 1.f:0.f;
  if (mode==1) return ((const int*)p)[idx]!=0 ? 1.f:0.f;
  return ((const uint8_t*)p)[idx]!=0 ? 1.f:0.f;
}

// ================= kernel 0: mask modes -> hdr =================
__global__ void ltc_modes(const void* mk1,const void* smk1,const void* mk2,const void* smk2,int* hdr){
  __shared__ int cnt[8];
  const int tid=threadIdx.x;
  if (tid<8) cnt[tid]=0;
  __syncthreads();
  scan_mask(mk1, 4096, tid, &cnt[0], &cnt[1]);
  scan_mask(smk1,2048, tid, &cnt[2], &cnt[3]);
  scan_mask(mk2, 1024, tid, &cnt[4], &cnt[5]);
  scan_mask(smk2,1024, tid, &cnt[6], &cnt[7]);
  __syncthreads();
  if (tid==0){
    hdr[0]=decide_mode(cnt[0],cnt[1],4096);
    hdr[1]=decide_mode(cnt[2],cnt[3],2048);
    hdr[2]=decide_mode(cnt[4],cnt[5],1024);
    hdr[3]=decide_mode(cnt[6],cnt[7],1024);
  }
}

// ================= kernel 1: precompute conv + L1 synapse sums =================
__global__ __launch_bounds__(256,2)
void ltc_pre(LtcArgs a, const int* __restrict__ hdr, float2* __restrict__ pre)
{
  const int b=blockIdx.x, tb=blockIdx.y*64, tid=threadIdx.x;
  const int mds1=hdr[1];
  __shared__ float us[4][32];

  const int j = tid&63;
  float As[32],Bs[32],Ws[32],Es[32];
  #pragma unroll
  for (int e=0;e<32;e++){
    const int idx=e*64+j;
    const float s=a.ssg1[idx];
    As[e]=-s*LOG2E; Bs[e]=s*a.smu1[idx]*LOG2E;
    const float wm=a.sw1[idx]*mask_at(a.smk1,mds1,idx);
    Ws[e]=wm; Es[e]=wm*a.ser1[idx];
  }
  const int th=tid>>5, f=tid&31, cc=f>>2, cwp=f&3;
  float k1[12],b1[4],k2[12],cb2=0.f,wi=0.f,bi=0.f;
  if (tid<128){
    #pragma unroll
    for (int q=0;q<12;q++) k1[q]=a.c1w[q];
    #pragma unroll
    for (int q=0;q<4;q++)  b1[q]=a.c1b[q];
    #pragma unroll
    for (int q=0;q<12;q++) k2[q]=a.c2w[cc*12+q];
    cb2=a.c2b[cc]; wi=a.iw1[f]; bi=a.ib1[f];
  }

  for (int tt=0; tt<64; tt+=4){
    if (tid<128){
      const int t=tb+tt+th;
      const float4* xg=(const float4*)(a.x + ((size_t)b*1024 + t)*8);
      float4 xa=xg[0], xb=xg[1];
      float xr[8]={xa.x,xa.y,xa.z,xa.w,xb.x,xb.y,xb.z,xb.w};
      float acc=cb2;
      #pragma unroll
      for (int ci=0;ci<4;ci++){
        const float q0=k1[ci*3],q1=k1[ci*3+1],q2=k1[ci*3+2],bb=b1[ci];
        #pragma unroll
        for (int kk=0;kk<3;kk++){
          const int p=cwp+kk;
          float h=fmaf(q0,xr[p],fmaf(q1,xr[p+1],fmaf(q2,xr[p+2],bb)));
          h=fmaxf(h,0.f);
          acc=fmaf(k2[ci*3+kk],h,acc);
        }
      }
      us[th][f]=fmaf(acc,wi,bi);
    }
    __syncthreads();
    {
      const int t4=tid>>6;
      float wns=0.f,wds=0.f;
      #pragma unroll
      for (int e=0;e<32;e++){
        const float u=us[t4][e];
        const float z=fmaf(As[e],u,Bs[e]);
        const float sg=frcp(1.f+fexp2(z));
        wds=fmaf(Ws[e],sg,wds);
        wns=fmaf(Es[e],sg,wns);
      }
      pre[((size_t)((b<<10)+tb+tt+t4))*64 + j] = make_float2(wns,wds);
    }
    __syncthreads();
  }
}

// ================= kernel 2: sequential scan (R0-verified structure) =================
// 256 blocks x 512 thr. Waves 0-3: L1 (lane=neuron, ranks mod 4, 11 uncond
// compacted slots + rare guarded tail). Waves 4-7: L2 pipelined one step
// behind, 4 unconditional slots. This 4+4 / 2-waves-per-SIMD layout is the
// measured local optimum (R2/R4/R6/R7 restructures all regressed: 1/SIMD
// exposes chain latency, >2/SIMD pays O(W) readback). Micro-opts vs the
// 3437us baseline: (a) pre-shifted bpermute byte indices (saves a v_lshl per
// gather on the critical wave); (b) s_setprio(1) on L1 waves only — each SIMD
// hosts one critical L1 wave + one slack L2 wave, so priority biases issue
// arbitration toward the barrier-critical wave (T5 mechanism, role-diverse).
// R3: no LDS float atomics. R4: no serial reducer. R6: no LDS v-gather/shfl.
__global__ __launch_bounds__(512,1)
void ltc_scan(LtcArgs a, const float2* __restrict__ pre, const int* __restrict__ hdr)
{
  const int b=blockIdx.x, tid=threadIdx.x;
  const int w=tid>>6, l=tid&63;
  const bool L1g = (w<4);

  __shared__ float2 p1[2][4][64];    // L1 partials (sn,sd)
  __shared__ float2 p2[2][8][32];    // L2 unfold partials
  __shared__ float2 pb[8][32];       // L2 synapse partials
  __shared__ float  v1buf[64];

  const int md1=hdr[0], md2=hdr[2], mds2=hdr[3];

  // L1 compacted: 16 slots, wave w takes ranks == w (mod 4); zero-padded.
  float A[16],B[16],W[16],E[16]; int I[16];
  // L2 compacted: 4 slots each (ranks == c mod 8 over 32 inputs); zero-padded.
  float A2[4],B2[4],W2[4],E2[4]; int I2[4];
  float As2[4],Bs2[4],Ws2[4],Es2[4]; int Is2[4];
  float cmt,gl,gv;
  int j2=0, c=0;
  int c1max=0;
  float2 cur=make_float2(0.f,0.f), nxt=make_float2(0.f,0.f);

  if (L1g){
    #pragma unroll
    for (int q=0;q<16;q++){ A[q]=0.f;B[q]=0.f;W[q]=0.f;E[q]=0.f;I[q]=0; }
    unsigned long long mm=0ull;
    for (int e=0;e<64;e++)
      if (mask_at(a.mk1,md1,e*64+l)!=0.f) mm |= (1ull<<e);
    int r=0, cnt=0;
    while (mm){
      const int e=(int)__builtin_ctzll(mm); mm&=mm-1;
      if ((r&3)==w && cnt<16){
        const int idx=e*64+l;
        const float s=a.sg1[idx];
        A[cnt]=-s*LOG2E; B[cnt]=s*a.mu1[idx]*LOG2E;
        const float wmv=a.w1[idx];
        W[cnt]=wmv; E[cnt]=wmv*a.er1[idx];
        I[cnt]=e<<2;                      // pre-shifted bpermute byte index
        cnt++;
      }
      r++;
    }
    c1max = wave_max(cnt);
    cmt=a.cm1[l]*6.f; gl=a.g1[l]; gv=gl*a.vl1[l];
    cur = pre[((size_t)(b<<10))*64 + l];
  } else {
    j2 = l&31; c = ((w-4)<<1) + (l>>5);
    #pragma unroll
    for (int q=0;q<4;q++){ A2[q]=0.f;B2[q]=0.f;W2[q]=0.f;E2[q]=0.f;I2[q]=0;
                           As2[q]=0.f;Bs2[q]=0.f;Ws2[q]=0.f;Es2[q]=0.f;Is2[q]=0; }
    { // main synapse (mk2): ranks == c (mod 8); 4 slots covers nnz<=32 exactly
      unsigned mm=0u;
      for (int e=0;e<32;e++)
        if (mask_at(a.mk2,md2,e*32+j2)!=0.f) mm |= (1u<<e);
      int r=0, cnt=0;
      while (mm){
        const int e=(int)__builtin_ctz(mm); mm&=mm-1;
        if ((r&7)==c && cnt<4){
          const int idx=e*32+j2;
          const float s=a.sg2[idx];
          A2[cnt]=-s*LOG2E; B2[cnt]=s*a.mu2[idx]*LOG2E;
          const float wmv=a.w2[idx];
          W2[cnt]=wmv; E2[cnt]=wmv*a.er2[idx];
          I2[cnt]=e<<2;                   // pre-shifted bpermute byte index
          cnt++;
        }
        r++;
      }
    }
    { // sensory synapse (smk2), input-affine folded (verified)
      unsigned mm=0u;
      for (int e=0;e<32;e++)
        if (mask_at(a.smk2,mds2,e*32+j2)!=0.f) mm |= (1u<<e);
      int r=0, cnt=0;
      while (mm){
        const int e=(int)__builtin_ctz(mm); mm&=mm-1;
        if ((r&7)==c && cnt<4){
          const int idx=e*32+j2;
          const float s=a.ssg2[idx];
          float Aq=-s*LOG2E, Bq=s*a.smu2[idx]*LOG2E;
          const float wi=a.ow1[e]*a.iw2[e];
          const float ci=fmaf(a.ob1[e],a.iw2[e],a.ib2[e]);
          Bq=fmaf(Aq,ci,Bq); Aq*=wi;
          As2[cnt]=Aq; Bs2[cnt]=Bq;
          const float wmv=a.sw2[idx];
          Ws2[cnt]=wmv; Es2[cnt]=wmv*a.ser2[idx];
          Is2[cnt]=e;                     // LDS index (unshifted)
          cnt++;
        }
        r++;
      }
    }
    cmt=a.cm2[j2]*6.f; gl=a.g2[j2]; gv=gl*a.vl2[j2];
  }

  float v1=0.f, v2=0.f;
  float bn=0.f, bdb=1.f;

  // L1 waves are the barrier-critical stragglers; bias CU issue arbitration.
  if (L1g) __builtin_amdgcn_s_setprio(1);

  #pragma unroll 1
  for (int t=0;t<1026;t++){
    const bool l1act = L1g && (t<1024);
    const bool l2syn = (!L1g) && (t>=1) && (t<=1024);
    const bool l2u5  = (!L1g) && (t>=2);
    #pragma unroll
    for (int k=0;k<6;k++){
      const int buf = k&1;
      // ---------- pre-barrier: partial sums ----------
      if (l1act){
        float sn0=0.f,sn1=0.f,sd0=0.f,sd1=0.f;
        #pragma unroll
        for (int q=0;q<11;q++){            // branch-free common path
          const float vv=gatherb(v1, I[q]);
          const float z=fmaf(A[q],vv,B[q]);
          const float sg=frcp(1.f+fexp2(z));
          if (q&1){ sd1=fmaf(W[q],sg,sd1); sn1=fmaf(E[q],sg,sn1); }
          else    { sd0=fmaf(W[q],sg,sd0); sn0=fmaf(E[q],sg,sn0); }
        }
        if (c1max>11){                      // rare tail (nnz>44 in some column)
          #pragma unroll
          for (int q=11;q<16;q++){
            if (q<c1max){
              const float vv=gatherb(v1, I[q]);
              const float z=fmaf(A[q],vv,B[q]);
              const float sg=frcp(1.f+fexp2(z));
              sd0=fmaf(W[q],sg,sd0); sn0=fmaf(E[q],sg,sn0);
            }
          }
        }
        p1[buf][w][l]=make_float2(sn0+sn1, sd0+sd1);
      } else if (!L1g){
        const bool go = (k==0) ? l2u5 : l2syn;
        if (go){
          float sn=0.f, sd=0.f;
          #pragma unroll
          for (int q=0;q<4;q++){            // branch-free
            const float vv=gatherb(v2, I2[q]);
            const float z=fmaf(A2[q],vv,B2[q]);
            const float sg=frcp(1.f+fexp2(z));
            sd=fmaf(W2[q],sg,sd);
            sn=fmaf(E2[q],sg,sn);
          }
          p2[buf][c][j2]=make_float2(sn,sd);
        }
      }
      __syncthreads();
      // ---------- post-barrier: reductions + state update ----------
      if (l1act){
        if (k==0){
          bn = gv + cur.x;
          bdb = cmt + gl + cur.y + 1e-8f;
          if (t+1<1024) nxt = pre[((size_t)((b<<10)+t+1))*64 + l];
        }
        const float2 q0=p1[buf][0][l], q1=p1[buf][1][l], q2=p1[buf][2][l], q3=p1[buf][3][l];
        const float sn = (q0.x+q1.x)+(q2.x+q3.x);
        const float sd = (q0.y+q1.y)+(q2.y+q3.y);
        v1 = (fmaf(cmt,v1,bn)+sn) * frcp(bdb+sd);
        if (k==5){
          if (w==0) v1buf[l]=v1;
          cur=nxt;
        }
      } else if (!L1g){
        if (k==0){
          if (l2u5){
            float2 s0=p2[buf][0][j2], s1=p2[buf][1][j2], s2=p2[buf][2][j2], s3=p2[buf][3][j2];
            float2 s4=p2[buf][4][j2], s5=p2[buf][5][j2], s6=p2[buf][6][j2], s7=p2[buf][7][j2];
            const float sn=((s0.x+s1.x)+(s2.x+s3.x))+((s4.x+s5.x)+(s6.x+s7.x));
            const float sd=((s0.y+s1.y)+(s2.y+s3.y))+((s4.y+s5.y)+(s6.y+s7.y));
            v2 = (fmaf(cmt,v2,bn)+sn) * frcp(bdb+sd);   // finishes step t-2
          }
          if (l2syn){
            float ssn=0.f, ssd=0.f;
            #pragma unroll
            for (int q=0;q<4;q++){          // branch-free
              const float vb=v1buf[Is2[q]];              // v1(t-1)
              const float z=fmaf(As2[q],vb,Bs2[q]);
              const float sg=frcp(1.f+fexp2(z));
              ssd=fmaf(Ws2[q],sg,ssd);
              ssn=fmaf(Es2[q],sg,ssn);
            }
            pb[c][j2]=make_float2(ssn,ssd);
          }
        }
        if (k>=1 && l2syn){
          if (k==1){
            float2 s0=pb[0][j2], s1=pb[1][j2], s2=pb[2][j2], s3=pb[3][j2];
            float2 s4=pb[4][j2], s5=pb[5][j2], s6=pb[6][j2], s7=pb[7][j2];
            const float wns=((s0.x+s1.x)+(s2.x+s3.x))+((s4.x+s5.x)+(s6.x+s7.x));
            const float wds=((s0.y+s1.y)+(s2.y+s3.y))+((s4.y+s5.y)+(s6.y+s7.y));
            bn = gv + wns;
            bdb = cmt + gl + wds + 1e-8f;
          }
          float2 s0=p2[buf][0][j2], s1=p2[buf][1][j2], s2=p2[buf][2][j2], s3=p2[buf][3][j2];
          float2 s4=p2[buf][4][j2], s5=p2[buf][5][j2], s6=p2[buf][6][j2], s7=p2[buf][7][j2];
          const float sn=((s0.x+s1.x)+(s2.x+s3.x))+((s4.x+s5.x)+(s6.x+s7.x));
          const float sd=((s0.y+s1.y)+(s2.y+s3.y))+((s4.y+s5.y)+(s6.y+s7.y));
          v2 = (fmaf(cmt,v2,bn)+sn) * frcp(bdb+sd);     // unfold k-1 of step t-1
        }
      }
    }
  }

  if (w==4 && l<16){
    float o = fmaf(v2, a.ow2[l], a.ob2[l]) * a.fcw[l];
    o += __shfl_xor(o,1); o += __shfl_xor(o,2); o += __shfl_xor(o,4); o += __shfl_xor(o,8);
    if (l==0){
      const float z = o + a.fcb[0];
      a.out[b] = frcp(1.f + fexp2(-z*LOG2E));
    }
  }
}

// ================= fallback: fused kernel (verified) =================
__global__ __launch_bounds__(256,1)
void ltc_fused(LtcArgs a)
{
  const int b=blockIdx.x, tid=threadIdx.x;
  __shared__ __align__(16) float xs[8192];
  __shared__ __align__(16) float v1s[2][64];
  __shared__ __align__(16) float v2s[2][32];
  __shared__ __align__(16) float u1s[8][32];
  __shared__ float cwts[184];
  __shared__ int cnt[8];

  {
    const float4* xg=(const float4*)(a.x + (size_t)b*8192);
    float4* xd=(float4*)xs;
    #pragma unroll
    for (int k=0;k<8;k++) xd[tid+256*k]=xg[tid+256*k];
  }
  if (tid<8) cnt[tid]=0;
  if (tid<64){ v1s[0][tid]=0.f; v1s[1][tid]=0.f; }
  if (tid<32){ v2s[0][tid]=0.f; v2s[1][tid]=0.f; }
  if (tid<12) cwts[tid]=a.c1w[tid];
  else if (tid<16)  cwts[tid]=a.c1b[tid-12];
  else if (tid<112) cwts[tid]=a.c2w[tid-16];
  else if (tid<120) cwts[tid]=a.c2b[tid-112];
  else if (tid<152) cwts[tid]=a.iw1[tid-120];
  else if (tid<184) cwts[tid]=a.ib1[tid-152];
  __syncthreads();

  scan_mask(a.mk1, 4096, tid, &cnt[0], &cnt[1]);
  scan_mask(a.smk1,2048, tid, &cnt[2], &cnt[3]);
  scan_mask(a.mk2, 1024, tid, &cnt[4], &cnt[5]);
  scan_mask(a.smk2,1024, tid, &cnt[6], &cnt[7]);
  __syncthreads();
  const int md1 =decide_mode(cnt[0],cnt[1],4096);
  const int mds1=decide_mode(cnt[2],cnt[3],2048);
  const int md2 =decide_mode(cnt[4],cnt[5],1024);
  const int mds2=decide_mode(cnt[6],cnt[7],1024);

  const int j1=tid>>2, ig1=tid&3;
  float Au[16],Bu[16],Wu[16],Eu[16];
  #pragma unroll
  for (int e=0;e<16;e++){
    const int i=16*ig1+e, idx=i*64+j1;
    const float s=a.sg1[idx];
    Au[e]=-s*LOG2E; Bu[e]=s*a.mu1[idx]*LOG2E;
    const float wm=a.w1[idx]*mask_at(a.mk1,md1,idx);
    Wu[e]=wm; Eu[e]=wm*a.er1[idx];
  }
  float As[8],Bs[8],Ws[8],Es[8];
  #pragma unroll
  for (int e=0;e<8;e++){
    const int i=8*ig1+e, idx=i*64+j1;
    const float s=a.ssg1[idx];
    As[e]=-s*LOG2E; Bs[e]=s*a.smu1[idx]*LOG2E;
    const float wm=a.sw1[idx]*mask_at(a.smk1,mds1,idx);
    Ws[e]=wm; Es[e]=wm*a.ser1[idx];
  }
  const float cmt1=a.cm1[j1]*6.f, gl1=a.g1[j1], gv1=gl1*a.vl1[j1];

  const int j2=tid>>3, ig2=tid&7;
  float A2[4],B2[4],W2[4],E2[4],A2s[4],B2s[4],W2s[4],E2s[4],Wi2[4],Ci2[4];
  #pragma unroll
  for (int e=0;e<4;e++){
    const int i=4*ig2+e, idx=i*32+j2;
    { const float s=a.sg2[idx];
      A2[e]=-s*LOG2E; B2[e]=s*a.mu2[idx]*LOG2E;
      const float wm=a.w2[idx]*mask_at(a.mk2,md2,idx);
      W2[e]=wm; E2[e]=wm*a.er2[idx]; }
    { const float s=a.ssg2[idx];
      A2s[e]=-s*LOG2E; B2s[e]=s*a.smu2[idx]*LOG2E;
      const float wm=a.sw2[idx]*mask_at(a.smk2,mds2,idx);
      W2s[e]=wm; E2s[e]=wm*a.ser2[idx]; }
    Wi2[e]=a.ow1[i]*a.iw2[i];
    Ci2[e]=fmaf(a.ob1[i],a.iw2[i],a.ib2[i]);
  }
  const float cmt2=a.cm2[j2]*6.f, gl2=a.g2[j2], gv2=gl2*a.vl2[j2];

  float vj1=0.f, vj2=0.f;
  int p1x=0, p2x=0;
  const int cf=tid&31, cc=cf>>2, cwp=cf&3, ctc=tid>>5;

  for (int t=0;t<1024;t++){
    if ((t&7)==0){
      const float* xr = &xs[(t+ctc)*8];
      float acc = cwts[112+cc];
      #pragma unroll
      for (int ci=0;ci<4;ci++){
        const float k10=cwts[ci*3], k11=cwts[ci*3+1], k12=cwts[ci*3+2], bb=cwts[12+ci];
        #pragma unroll
        for (int kk=0;kk<3;kk++){
          const int p=cwp+kk;
          float h = fmaf(k10,xr[p], fmaf(k11,xr[p+1], fmaf(k12,xr[p+2], bb)));
          h = fmaxf(h,0.f);
          acc = fmaf(cwts[16+(cc*4+ci)*3+kk], h, acc);
        }
      }
      u1s[ctc][cf] = fmaf(acc, cwts[120+cf], cwts[152+cf]);
      __syncthreads();
    }

    float wns=0.f, wds=0.f;
    {
      const float4* uv4=(const float4*)&u1s[t&7][8*ig1];
      float4 qa=uv4[0], qb=uv4[1];
      float uvv[8]={qa.x,qa.y,qa.z,qa.w,qb.x,qb.y,qb.z,qb.w};
      #pragma unroll
      for (int e=0;e<8;e++){
        float z=fmaf(As[e],uvv[e],Bs[e]);
        float sg=frcp(1.f+fexp2(z));
        wds=fmaf(Ws[e],sg,wds);
        wns=fmaf(Es[e],sg,wns);
      }
      wns += __shfl_xor(wns,1); wns += __shfl_xor(wns,2);
      wds += __shfl_xor(wds,1); wds += __shfl_xor(wds,2);
    }
    const float bn1 = gv1 + wns;
    const float bd1 = cmt1 + gl1 + wds + 1e-8f;

    #pragma unroll
    for (int k=0;k<6;k++){
      const float4* vv4=(const float4*)&v1s[p1x][16*ig1];
      float4 q0=vv4[0], q1=vv4[1], q2=vv4[2], q3=vv4[3];
      float vi[16]={q0.x,q0.y,q0.z,q0.w,q1.x,q1.y,q1.z,q1.w,
                    q2.x,q2.y,q2.z,q2.w,q3.x,q3.y,q3.z,q3.w};
      float sn=0.f, sd=0.f;
      #pragma unroll
      for (int e=0;e<16;e++){
        float z=fmaf(Au[e],vi[e],Bu[e]);
        float sg=frcp(1.f+fexp2(z));
        sd=fmaf(Wu[e],sg,sd);
        sn=fmaf(Eu[e],sg,sn);
      }
      sn += __shfl_xor(sn,1); sn += __shfl_xor(sn,2);
      sd += __shfl_xor(sd,1); sd += __shfl_xor(sd,2);
      vj1 = (fmaf(cmt1,vj1,bn1)+sn) * frcp(bd1+sd);
      p1x ^= 1;
      if (ig1==0) v1s[p1x][j1]=vj1;
      __syncthreads();
    }

    float wns2=0.f, wds2=0.f;
    {
      const float4* vf4=(const float4*)&v1s[p1x][4*ig2];
      float4 vf=vf4[0];
      float vin[4]={vf.x,vf.y,vf.z,vf.w};
      #pragma unroll
      for (int e=0;e<4;e++){
        float u2=fmaf(vin[e],Wi2[e],Ci2[e]);
        float z=fmaf(A2s[e],u2,B2s[e]);
        float sg=frcp(1.f+fexp2(z));
        wds2=fmaf(W2s[e],sg,wds2);
        wns2=fmaf(E2s[e],sg,wns2);
      }
      wns2 += __shfl_xor(wns2,1); wns2 += __shfl_xor(wns2,2); wns2 += __shfl_xor(wns2,4);
      wds2 += __shfl_xor(wds2,1); wds2 += __shfl_xor(wds2,2); wds2 += __shfl_xor(wds2,4);
    }
    const float bn2 = gv2 + wns2;
    const float bd2 = cmt2 + gl2 + wds2 + 1e-8f;

    #pragma unroll
    for (int k=0;k<6;k++){
      const float4* vv4=(const float4*)&v2s[p2x][4*ig2];
      float4 q=vv4[0];
      float vi[4]={q.x,q.y,q.z,q.w};
      float sn=0.f, sd=0.f;
      #pragma unroll
      for (int e=0;e<4;e++){
        float z=fmaf(A2[e],vi[e],B2[e]);
        float sg=frcp(1.f+fexp2(z));
        sd=fmaf(W2[e],sg,sd);
        sn=fmaf(E2[e],sg,sn);
      }
      sn += __shfl_xor(sn,1); sn += __shfl_xor(sn,2); sn += __shfl_xor(sn,4);
      sd += __shfl_xor(sd,1); sd += __shfl_xor(sd,2); sd += __shfl_xor(sd,4);
      vj2 = (fmaf(cmt2,vj2,bn2)+sn) * frcp(bd2+sd);
      p2x ^= 1;
      if (ig2==0) v2s[p2x][j2]=vj2;
      __syncthreads();
    }
  }

  if (tid<16){
    float o = fmaf(v2s[p2x][tid], a.ow2[tid], a.ob2[tid]) * a.fcw[tid];
    o += __shfl_xor(o,1); o += __shfl_xor(o,2); o += __shfl_xor(o,4); o += __shfl_xor(o,8);
    if (tid==0){
      float z = o + a.fcb[0];
      a.out[b] = frcp(1.f + fexp2(-z*LOG2E));
    }
  }
}

extern "C" void kernel_launch(void* const* d_in, const int* in_sizes, int n_in,
                              void* d_out, int out_size, void* d_ws, size_t ws_size,
                              hipStream_t stream)
{
  (void)out_size;
  int o[41];
  for (int i=0;i<41;i++) o[i]=i;
  if (n_in>=41 && in_sizes[20]!=4096){
    for (int i=0;i<15;i++) o[5+i]=5+i;
    o[20]=37; o[21]=38;
    for (int i=0;i<15;i++) o[22+i]=20+i;
    o[37]=39; o[38]=40;
    o[39]=35; o[40]=36;
  }
  const float* F[41];
  for (int i=0;i<41;i++) F[i]=(const float*)d_in[o[i]];
  LtcArgs a;
  a.x=F[0]; a.c1w=F[1]; a.c1b=F[2]; a.c2w=F[3]; a.c2b=F[4];
  a.g1=F[5]; a.vl1=F[6]; a.cm1=F[7]; a.sg1=F[8]; a.mu1=F[9]; a.w1=F[10]; a.er1=F[11];
  a.ssg1=F[12]; a.smu1=F[13]; a.sw1=F[14]; a.ser1=F[15];
  a.iw1=F[16]; a.ib1=F[17]; a.ow1=F[18]; a.ob1=F[19];
  a.mk1=(const void*)d_in[o[20]]; a.smk1=(const void*)d_in[o[21]];
  a.g2=F[22]; a.vl2=F[23]; a.cm2=F[24]; a.sg2=F[25]; a.mu2=F[26]; a.w2=F[27]; a.er2=F[28];
  a.ssg2=F[29]; a.smu2=F[30]; a.sw2=F[31]; a.ser2=F[32];
  a.iw2=F[33]; a.ib2=F[34]; a.ow2=F[35]; a.ob2=F[36];
  a.mk2=(const void*)d_in[o[37]]; a.smk2=(const void*)d_in[o[38]];
  a.fcw=F[39]; a.fcb=F[40];
  a.out=(float*)d_out;

  const size_t need = 256 + (size_t)256*1024*64*sizeof(float2);
  if (ws_size >= need){
    int* hdr = (int*)d_ws;
    float2* pre = (float2*)((char*)d_ws + 256);
    ltc_modes<<<dim3(1),dim3(256),0,stream>>>(a.mk1,a.smk1,a.mk2,a.smk2,hdr);
    ltc_pre<<<dim3(256,16),dim3(256),0,stream>>>(a,hdr,pre);
    ltc_scan<<<dim3(256),dim3(512),0,stream>>>(a,pre,hdr);
  } else {
    ltc_fused<<<dim3(256),dim3(256),0,stream>>>(a);
  }
}

// Round 9
// 3575.993 us; speedup vs baseline: 1.4517x; 1.0093x over previous
//
#include <hip/hip_runtime.h>
#include <stdint.h>

#define LOG2E 1.44269504088896340736f

struct LtcArgs {
  const float *x, *c1w, *c1b, *c2w, *c2b;
  const float *g1,*vl1,*cm1,*sg1,*mu1,*w1,*er1,*ssg1,*smu1,*sw1,*ser1,*iw1,*ib1,*ow1,*ob1;
  const void  *mk1,*smk1;
  const float *g2,*vl2,*cm2,*sg2,*mu2,*w2,*er2,*ssg2,*smu2,*sw2,*ser2,*iw2,*ib2,*ow2,*ob2;
  const void  *mk2,*smk2;
  const float *fcw,*fcb;
  float *out;
};

__device__ __forceinline__ float fexp2(float v){ return __builtin_amdgcn_exp2f(v); }
__device__ __forceinline__ float frcp (float v){ return __builtin_amdgcn_rcpf(v); }
// per-lane variable gather within the wave (ds_bpermute); index is PRE-SHIFTED byte addr
__device__ __forceinline__ float gatherb(float v, int byteLane){
  return __int_as_float(__builtin_amdgcn_ds_bpermute(byteLane, __float_as_int(v)));
}
__device__ __forceinline__ int wave_max(int v){
  #pragma unroll
  for (int s=1;s<64;s<<=1){ int o=__shfl_xor(v,s); v = o>v ? o : v; }
  return __builtin_amdgcn_readfirstlane(v);
}

// ---- mask dtype detection (verified: absmax 0) ----
__device__ __forceinline__ void scan_mask(const void* p, int n, int tid, int* cge2, int* cone){
  const uint8_t* bp = (const uint8_t*)p;
  int g=0,o=0;
  for (int k=tid;k<n;k+=256){ uint8_t v=bp[k]; g += (v>=2); o += (v==1); }
  if (g) atomicAdd(cge2,g);
  if (o) atomicAdd(cone,o);
}
__device__ __forceinline__ int decide_mode(int ge2,int one,int n){
  if (ge2 > (n>>4)) return 2;
  if (one > (n>>2)) return 0;
  return 1;
}
__device__ __forceinline__ float mask_at(const void* p,int mode,int idx){
  if (mode==2) return ((const float*)p)[idx]!=0.f ? 1.f:0.f;
  if (mode==1) return ((const int*)p)[idx]!=0 ? 1.f:0.f;
  return ((const uint8_t*)p)[idx]!=0 ? 1.f:0.f;
}

// ================= kernel 0: mask modes -> hdr =================
__global__ void ltc_modes(const void* mk1,const void* smk1,const void* mk2,const void* smk2,int* hdr){
  __shared__ int cnt[8];
  const int tid=threadIdx.x;
  if (tid<8) cnt[tid]=0;
  __syncthreads();
  scan_mask(mk1, 4096, tid, &cnt[0], &cnt[1]);
  scan_mask(smk1,2048, tid, &cnt[2], &cnt[3]);
  scan_mask(mk2, 1024, tid, &cnt[4], &cnt[5]);
  scan_mask(smk2,1024, tid, &cnt[6], &cnt[7]);
  __syncthreads();
  if (tid==0){
    hdr[0]=decide_mode(cnt[0],cnt[1],4096);
    hdr[1]=decide_mode(cnt[2],cnt[3],2048);
    hdr[2]=decide_mode(cnt[4],cnt[5],1024);
    hdr[3]=decide_mode(cnt[6],cnt[7],1024);
  }
}

// ================= kernel 1: precompute conv + L1 synapse sums =================
__global__ __launch_bounds__(256,2)
void ltc_pre(LtcArgs a, const int* __restrict__ hdr, float2* __restrict__ pre)
{
  const int b=blockIdx.x, tb=blockIdx.y*64, tid=threadIdx.x;
  const int mds1=hdr[1];
  __shared__ float us[4][32];

  const int j = tid&63;
  float As[32],Bs[32],Ws[32],Es[32];
  #pragma unroll
  for (int e=0;e<32;e++){
    const int idx=e*64+j;
    const float s=a.ssg1[idx];
    As[e]=-s*LOG2E; Bs[e]=s*a.smu1[idx]*LOG2E;
    const float wm=a.sw1[idx]*mask_at(a.smk1,mds1,idx);
    Ws[e]=wm; Es[e]=wm*a.ser1[idx];
  }
  const int th=tid>>5, f=tid&31, cc=f>>2, cwp=f&3;
  float k1[12],b1[4],k2[12],cb2=0.f,wi=0.f,bi=0.f;
  if (tid<128){
    #pragma unroll
    for (int q=0;q<12;q++) k1[q]=a.c1w[q];
    #pragma unroll
    for (int q=0;q<4;q++)  b1[q]=a.c1b[q];
    #pragma unroll
    for (int q=0;q<12;q++) k2[q]=a.c2w[cc*12+q];
    cb2=a.c2b[cc]; wi=a.iw1[f]; bi=a.ib1[f];
  }

  for (int tt=0; tt<64; tt+=4){
    if (tid<128){
      const int t=tb+tt+th;
      const float4* xg=(const float4*)(a.x + ((size_t)b*1024 + t)*8);
      float4 xa=xg[0], xb=xg[1];
      float xr[8]={xa.x,xa.y,xa.z,xa.w,xb.x,xb.y,xb.z,xb.w};
      float acc=cb2;
      #pragma unroll
      for (int ci=0;ci<4;ci++){
        const float q0=k1[ci*3],q1=k1[ci*3+1],q2=k1[ci*3+2],bb=b1[ci];
        #pragma unroll
        for (int kk=0;kk<3;kk++){
          const int p=cwp+kk;
          float h=fmaf(q0,xr[p],fmaf(q1,xr[p+1],fmaf(q2,xr[p+2],bb)));
          h=fmaxf(h,0.f);
          acc=fmaf(k2[ci*3+kk],h,acc);
        }
      }
      us[th][f]=fmaf(acc,wi,bi);
    }
    __syncthreads();
    {
      const int t4=tid>>6;
      float wns=0.f,wds=0.f;
      #pragma unroll
      for (int e=0;e<32;e++){
        const float u=us[t4][e];
        const float z=fmaf(As[e],u,Bs[e]);
        const float sg=frcp(1.f+fexp2(z));
        wds=fmaf(Ws[e],sg,wds);
        wns=fmaf(Es[e],sg,wns);
      }
      pre[((size_t)((b<<10)+tb+tt+t4))*64 + j] = make_float2(wns,wds);
    }
    __syncthreads();
  }
}

// ================= kernel 2: sequential scan (R0-verified structure) =================
// 256 blocks x 512 thr. Waves 0-3: L1 (lane=neuron, ranks mod 4, 11 uncond
// compacted slots + rare guarded tail). Waves 4-7: L2 pipelined one step
// behind, 4 unconditional slots. This 4+4 / 2-waves-per-SIMD layout is the
// measured local optimum (R2/R4/R6/R7 restructures all regressed: 1/SIMD
// exposes chain latency, >2/SIMD pays O(W) readback; R3 LDS float atomics
// catastrophic; R8 setprio on L1 waves regressed 2.5% — both waves are
// barrier-critical in different segments, so priority-starving L2 delays the
// block-wide barrier). Only retained micro-opt vs the 3437us baseline:
// pre-shifted bpermute byte indices (saves a v_lshl per gather on the
// critical wave; no register/schedule side-effects).
__global__ __launch_bounds__(512,1)
void ltc_scan(LtcArgs a, const float2* __restrict__ pre, const int* __restrict__ hdr)
{
  const int b=blockIdx.x, tid=threadIdx.x;
  const int w=tid>>6, l=tid&63;
  const bool L1g = (w<4);

  __shared__ float2 p1[2][4][64];    // L1 partials (sn,sd)
  __shared__ float2 p2[2][8][32];    // L2 unfold partials
  __shared__ float2 pb[8][32];       // L2 synapse partials
  __shared__ float  v1buf[64];

  const int md1=hdr[0], md2=hdr[2], mds2=hdr[3];

  // L1 compacted: 16 slots, wave w takes ranks == w (mod 4); zero-padded.
  float A[16],B[16],W[16],E[16]; int I[16];
  // L2 compacted: 4 slots each (ranks == c mod 8 over 32 inputs); zero-padded.
  float A2[4],B2[4],W2[4],E2[4]; int I2[4];
  float As2[4],Bs2[4],Ws2[4],Es2[4]; int Is2[4];
  float cmt,gl,gv;
  int j2=0, c=0;
  int c1max=0;
  float2 cur=make_float2(0.f,0.f), nxt=make_float2(0.f,0.f);

  if (L1g){
    #pragma unroll
    for (int q=0;q<16;q++){ A[q]=0.f;B[q]=0.f;W[q]=0.f;E[q]=0.f;I[q]=0; }
    unsigned long long mm=0ull;
    for (int e=0;e<64;e++)
      if (mask_at(a.mk1,md1,e*64+l)!=0.f) mm |= (1ull<<e);
    int r=0, cnt=0;
    while (mm){
      const int e=(int)__builtin_ctzll(mm); mm&=mm-1;
      if ((r&3)==w && cnt<16){
        const int idx=e*64+l;
        const float s=a.sg1[idx];
        A[cnt]=-s*LOG2E; B[cnt]=s*a.mu1[idx]*LOG2E;
        const float wmv=a.w1[idx];
        W[cnt]=wmv; E[cnt]=wmv*a.er1[idx];
        I[cnt]=e<<2;                      // pre-shifted bpermute byte index
        cnt++;
      }
      r++;
    }
    c1max = wave_max(cnt);
    cmt=a.cm1[l]*6.f; gl=a.g1[l]; gv=gl*a.vl1[l];
    cur = pre[((size_t)(b<<10))*64 + l];
  } else {
    j2 = l&31; c = ((w-4)<<1) + (l>>5);
    #pragma unroll
    for (int q=0;q<4;q++){ A2[q]=0.f;B2[q]=0.f;W2[q]=0.f;E2[q]=0.f;I2[q]=0;
                           As2[q]=0.f;Bs2[q]=0.f;Ws2[q]=0.f;Es2[q]=0.f;Is2[q]=0; }
    { // main synapse (mk2): ranks == c (mod 8); 4 slots covers nnz<=32 exactly
      unsigned mm=0u;
      for (int e=0;e<32;e++)
        if (mask_at(a.mk2,md2,e*32+j2)!=0.f) mm |= (1u<<e);
      int r=0, cnt=0;
      while (mm){
        const int e=(int)__builtin_ctz(mm); mm&=mm-1;
        if ((r&7)==c && cnt<4){
          const int idx=e*32+j2;
          const float s=a.sg2[idx];
          A2[cnt]=-s*LOG2E; B2[cnt]=s*a.mu2[idx]*LOG2E;
          const float wmv=a.w2[idx];
          W2[cnt]=wmv; E2[cnt]=wmv*a.er2[idx];
          I2[cnt]=e<<2;                   // pre-shifted bpermute byte index
          cnt++;
        }
        r++;
      }
    }
    { // sensory synapse (smk2), input-affine folded (verified)
      unsigned mm=0u;
      for (int e=0;e<32;e++)
        if (mask_at(a.smk2,mds2,e*32+j2)!=0.f) mm |= (1u<<e);
      int r=0, cnt=0;
      while (mm){
        const int e=(int)__builtin_ctz(mm); mm&=mm-1;
        if ((r&7)==c && cnt<4){
          const int idx=e*32+j2;
          const float s=a.ssg2[idx];
          float Aq=-s*LOG2E, Bq=s*a.smu2[idx]*LOG2E;
          const float wi=a.ow1[e]*a.iw2[e];
          const float ci=fmaf(a.ob1[e],a.iw2[e],a.ib2[e]);
          Bq=fmaf(Aq,ci,Bq); Aq*=wi;
          As2[cnt]=Aq; Bs2[cnt]=Bq;
          const float wmv=a.sw2[idx];
          Ws2[cnt]=wmv; Es2[cnt]=wmv*a.ser2[idx];
          Is2[cnt]=e;                     // LDS index (unshifted)
          cnt++;
        }
        r++;
      }
    }
    cmt=a.cm2[j2]*6.f; gl=a.g2[j2]; gv=gl*a.vl2[j2];
  }

  float v1=0.f, v2=0.f;
  float bn=0.f, bdb=1.f;

  #pragma unroll 1
  for (int t=0;t<1026;t++){
    const bool l1act = L1g && (t<1024);
    const bool l2syn = (!L1g) && (t>=1) && (t<=1024);
    const bool l2u5  = (!L1g) && (t>=2);
    #pragma unroll
    for (int k=0;k<6;k++){
      const int buf = k&1;
      // ---------- pre-barrier: partial sums ----------
      if (l1act){
        float sn0=0.f,sn1=0.f,sd0=0.f,sd1=0.f;
        #pragma unroll
        for (int q=0;q<11;q++){            // branch-free common path
          const float vv=gatherb(v1, I[q]);
          const float z=fmaf(A[q],vv,B[q]);
          const float sg=frcp(1.f+fexp2(z));
          if (q&1){ sd1=fmaf(W[q],sg,sd1); sn1=fmaf(E[q],sg,sn1); }
          else    { sd0=fmaf(W[q],sg,sd0); sn0=fmaf(E[q],sg,sn0); }
        }
        if (c1max>11){                      // rare tail (nnz>44 in some column)
          #pragma unroll
          for (int q=11;q<16;q++){
            if (q<c1max){
              const float vv=gatherb(v1, I[q]);
              const float z=fmaf(A[q],vv,B[q]);
              const float sg=frcp(1.f+fexp2(z));
              sd0=fmaf(W[q],sg,sd0); sn0=fmaf(E[q],sg,sn0);
            }
          }
        }
        p1[buf][w][l]=make_float2(sn0+sn1, sd0+sd1);
      } else if (!L1g){
        const bool go = (k==0) ? l2u5 : l2syn;
        if (go){
          float sn=0.f, sd=0.f;
          #pragma unroll
          for (int q=0;q<4;q++){            // branch-free
            const float vv=gatherb(v2, I2[q]);
            const float z=fmaf(A2[q],vv,B2[q]);
            const float sg=frcp(1.f+fexp2(z));
            sd=fmaf(W2[q],sg,sd);
            sn=fmaf(E2[q],sg,sn);
          }
          p2[buf][c][j2]=make_float2(sn,sd);
        }
      }
      __syncthreads();
      // ---------- post-barrier: reductions + state update ----------
      if (l1act){
        if (k==0){
          bn = gv + cur.x;
          bdb = cmt + gl + cur.y + 1e-8f;
          if (t+1<1024) nxt = pre[((size_t)((b<<10)+t+1))*64 + l];
        }
        const float2 q0=p1[buf][0][l], q1=p1[buf][1][l], q2=p1[buf][2][l], q3=p1[buf][3][l];
        const float sn = (q0.x+q1.x)+(q2.x+q3.x);
        const float sd = (q0.y+q1.y)+(q2.y+q3.y);
        v1 = (fmaf(cmt,v1,bn)+sn) * frcp(bdb+sd);
        if (k==5){
          if (w==0) v1buf[l]=v1;
          cur=nxt;
        }
      } else if (!L1g){
        if (k==0){
          if (l2u5){
            float2 s0=p2[buf][0][j2], s1=p2[buf][1][j2], s2=p2[buf][2][j2], s3=p2[buf][3][j2];
            float2 s4=p2[buf][4][j2], s5=p2[buf][5][j2], s6=p2[buf][6][j2], s7=p2[buf][7][j2];
            const float sn=((s0.x+s1.x)+(s2.x+s3.x))+((s4.x+s5.x)+(s6.x+s7.x));
            const float sd=((s0.y+s1.y)+(s2.y+s3.y))+((s4.y+s5.y)+(s6.y+s7.y));
            v2 = (fmaf(cmt,v2,bn)+sn) * frcp(bdb+sd);   // finishes step t-2
          }
          if (l2syn){
            float ssn=0.f, ssd=0.f;
            #pragma unroll
            for (int q=0;q<4;q++){          // branch-free
              const float vb=v1buf[Is2[q]];              // v1(t-1)
              const float z=fmaf(As2[q],vb,Bs2[q]);
              const float sg=frcp(1.f+fexp2(z));
              ssd=fmaf(Ws2[q],sg,ssd);
              ssn=fmaf(Es2[q],sg,ssn);
            }
            pb[c][j2]=make_float2(ssn,ssd);
          }
        }
        if (k>=1 && l2syn){
          if (k==1){
            float2 s0=pb[0][j2], s1=pb[1][j2], s2=pb[2][j2], s3=pb[3][j2];
            float2 s4=pb[4][j2], s5=pb[5][j2], s6=pb[6][j2], s7=pb[7][j2];
            const float wns=((s0.x+s1.x)+(s2.x+s3.x))+((s4.x+s5.x)+(s6.x+s7.x));
            const float wds=((s0.y+s1.y)+(s2.y+s3.y))+((s4.y+s5.y)+(s6.y+s7.y));
            bn = gv + wns;
            bdb = cmt + gl + wds + 1e-8f;
          }
          float2 s0=p2[buf][0][j2], s1=p2[buf][1][j2], s2=p2[buf][2][j2], s3=p2[buf][3][j2];
          float2 s4=p2[buf][4][j2], s5=p2[buf][5][j2], s6=p2[buf][6][j2], s7=p2[buf][7][j2];
          const float sn=((s0.x+s1.x)+(s2.x+s3.x))+((s4.x+s5.x)+(s6.x+s7.x));
          const float sd=((s0.y+s1.y)+(s2.y+s3.y))+((s4.y+s5.y)+(s6.y+s7.y));
          v2 = (fmaf(cmt,v2,bn)+sn) * frcp(bdb+sd);     // unfold k-1 of step t-1
        }
      }
    }
  }

  if (w==4 && l<16){
    float o = fmaf(v2, a.ow2[l], a.ob2[l]) * a.fcw[l];
    o += __shfl_xor(o,1); o += __shfl_xor(o,2); o += __shfl_xor(o,4); o += __shfl_xor(o,8);
    if (l==0){
      const float z = o + a.fcb[0];
      a.out[b] = frcp(1.f + fexp2(-z*LOG2E));
    }
  }
}

// ================= fallback: fused kernel (verified) =================
__global__ __launch_bounds__(256,1)
void ltc_fused(LtcArgs a)
{
  const int b=blockIdx.x, tid=threadIdx.x;
  __shared__ __align__(16) float xs[8192];
  __shared__ __align__(16) float v1s[2][64];
  __shared__ __align__(16) float v2s[2][32];
  __shared__ __align__(16) float u1s[8][32];
  __shared__ float cwts[184];
  __shared__ int cnt[8];

  {
    const float4* xg=(const float4*)(a.x + (size_t)b*8192);
    float4* xd=(float4*)xs;
    #pragma unroll
    for (int k=0;k<8;k++) xd[tid+256*k]=xg[tid+256*k];
  }
  if (tid<8) cnt[tid]=0;
  if (tid<64){ v1s[0][tid]=0.f; v1s[1][tid]=0.f; }
  if (tid<32){ v2s[0][tid]=0.f; v2s[1][tid]=0.f; }
  if (tid<12) cwts[tid]=a.c1w[tid];
  else if (tid<16)  cwts[tid]=a.c1b[tid-12];
  else if (tid<112) cwts[tid]=a.c2w[tid-16];
  else if (tid<120) cwts[tid]=a.c2b[tid-112];
  else if (tid<152) cwts[tid]=a.iw1[tid-120];
  else if (tid<184) cwts[tid]=a.ib1[tid-152];
  __syncthreads();

  scan_mask(a.mk1, 4096, tid, &cnt[0], &cnt[1]);
  scan_mask(a.smk1,2048, tid, &cnt[2], &cnt[3]);
  scan_mask(a.mk2, 1024, tid, &cnt[4], &cnt[5]);
  scan_mask(a.smk2,1024, tid, &cnt[6], &cnt[7]);
  __syncthreads();
  const int md1 =decide_mode(cnt[0],cnt[1],4096);
  const int mds1=decide_mode(cnt[2],cnt[3],2048);
  const int md2 =decide_mode(cnt[4],cnt[5],1024);
  const int mds2=decide_mode(cnt[6],cnt[7],1024);

  const int j1=tid>>2, ig1=tid&3;
  float Au[16],Bu[16],Wu[16],Eu[16];
  #pragma unroll
  for (int e=0;e<16;e++){
    const int i=16*ig1+e, idx=i*64+j1;
    const float s=a.sg1[idx];
    Au[e]=-s*LOG2E; Bu[e]=s*a.mu1[idx]*LOG2E;
    const float wm=a.w1[idx]*mask_at(a.mk1,md1,idx);
    Wu[e]=wm; Eu[e]=wm*a.er1[idx];
  }
  float As[8],Bs[8],Ws[8],Es[8];
  #pragma unroll
  for (int e=0;e<8;e++){
    const int i=8*ig1+e, idx=i*64+j1;
    const float s=a.ssg1[idx];
    As[e]=-s*LOG2E; Bs[e]=s*a.smu1[idx]*LOG2E;
    const float wm=a.sw1[idx]*mask_at(a.smk1,mds1,idx);
    Ws[e]=wm; Es[e]=wm*a.ser1[idx];
  }
  const float cmt1=a.cm1[j1]*6.f, gl1=a.g1[j1], gv1=gl1*a.vl1[j1];

  const int j2=tid>>3, ig2=tid&7;
  float A2[4],B2[4],W2[4],E2[4],A2s[4],B2s[4],W2s[4],E2s[4],Wi2[4],Ci2[4];
  #pragma unroll
  for (int e=0;e<4;e++){
    const int i=4*ig2+e, idx=i*32+j2;
    { const float s=a.sg2[idx];
      A2[e]=-s*LOG2E; B2[e]=s*a.mu2[idx]*LOG2E;
      const float wm=a.w2[idx]*mask_at(a.mk2,md2,idx);
      W2[e]=wm; E2[e]=wm*a.er2[idx]; }
    { const float s=a.ssg2[idx];
      A2s[e]=-s*LOG2E; B2s[e]=s*a.smu2[idx]*LOG2E;
      const float wm=a.sw2[idx]*mask_at(a.smk2,mds2,idx);
      W2s[e]=wm; E2s[e]=wm*a.ser2[idx]; }
    Wi2[e]=a.ow1[i]*a.iw2[i];
    Ci2[e]=fmaf(a.ob1[i],a.iw2[i],a.ib2[i]);
  }
  const float cmt2=a.cm2[j2]*6.f, gl2=a.g2[j2], gv2=gl2*a.vl2[j2];

  float vj1=0.f, vj2=0.f;
  int p1x=0, p2x=0;
  const int cf=tid&31, cc=cf>>2, cwp=cf&3, ctc=tid>>5;

  for (int t=0;t<1024;t++){
    if ((t&7)==0){
      const float* xr = &xs[(t+ctc)*8];
      float acc = cwts[112+cc];
      #pragma unroll
      for (int ci=0;ci<4;ci++){
        const float k10=cwts[ci*3], k11=cwts[ci*3+1], k12=cwts[ci*3+2], bb=cwts[12+ci];
        #pragma unroll
        for (int kk=0;kk<3;kk++){
          const int p=cwp+kk;
          float h = fmaf(k10,xr[p], fmaf(k11,xr[p+1], fmaf(k12,xr[p+2], bb)));
          h = fmaxf(h,0.f);
          acc = fmaf(cwts[16+(cc*4+ci)*3+kk], h, acc);
        }
      }
      u1s[ctc][cf] = fmaf(acc, cwts[120+cf], cwts[152+cf]);
      __syncthreads();
    }

    float wns=0.f, wds=0.f;
    {
      const float4* uv4=(const float4*)&u1s[t&7][8*ig1];
      float4 qa=uv4[0], qb=uv4[1];
      float uvv[8]={qa.x,qa.y,qa.z,qa.w,qb.x,qb.y,qb.z,qb.w};
      #pragma unroll
      for (int e=0;e<8;e++){
        float z=fmaf(As[e],uvv[e],Bs[e]);
        float sg=frcp(1.f+fexp2(z));
        wds=fmaf(Ws[e],sg,wds);
        wns=fmaf(Es[e],sg,wns);
      }
      wns += __shfl_xor(wns,1); wns += __shfl_xor(wns,2);
      wds += __shfl_xor(wds,1); wds += __shfl_xor(wds,2);
    }
    const float bn1 = gv1 + wns;
    const float bd1 = cmt1 + gl1 + wds + 1e-8f;

    #pragma unroll
    for (int k=0;k<6;k++){
      const float4* vv4=(const float4*)&v1s[p1x][16*ig1];
      float4 q0=vv4[0], q1=vv4[1], q2=vv4[2], q3=vv4[3];
      float vi[16]={q0.x,q0.y,q0.z,q0.w,q1.x,q1.y,q1.z,q1.w,
                    q2.x,q2.y,q2.z,q2.w,q3.x,q3.y,q3.z,q3.w};
      float sn=0.f, sd=0.f;
      #pragma unroll
      for (int e=0;e<16;e++){
        float z=fmaf(Au[e],vi[e],Bu[e]);
        float sg=frcp(1.f+fexp2(z));
        sd=fmaf(Wu[e],sg,sd);
        sn=fmaf(Eu[e],sg,sn);
      }
      sn += __shfl_xor(sn,1); sn += __shfl_xor(sn,2);
      sd += __shfl_xor(sd,1); sd += __shfl_xor(sd,2);
      vj1 = (fmaf(cmt1,vj1,bn1)+sn) * frcp(bd1+sd);
      p1x ^= 1;
      if (ig1==0) v1s[p1x][j1]=vj1;
      __syncthreads();
    }

    float wns2=0.f, wds2=0.f;
    {
      const float4* vf4=(const float4*)&v1s[p1x][4*ig2];
      float4 vf=vf4[0];
      float vin[4]={vf.x,vf.y,vf.z,vf.w};
      #pragma unroll
      for (int e=0;e<4;e++){
        float u2=fmaf(vin[e],Wi2[e],Ci2[e]);
        float z=fmaf(A2s[e],u2,B2s[e]);
        float sg=frcp(1.f+fexp2(z));
        wds2=fmaf(W2s[e],sg,wds2);
        wns2=fmaf(E2s[e],sg,wns2);
      }
      wns2 += __shfl_xor(wns2,1); wns2 += __shfl_xor(wns2,2); wns2 += __shfl_xor(wns2,4);
      wds2 += __shfl_xor(wds2,1); wds2 += __shfl_xor(wds2,2); wds2 += __shfl_xor(wds2,4);
    }
    const float bn2 = gv2 + wns2;
    const float bd2 = cmt2 + gl2 + wds2 + 1e-8f;

    #pragma unroll
    for (int k=0;k<6;k++){
      const float4* vv4=(const float4*)&v2s[p2x][4*ig2];
      float4 q=vv4[0];
      float vi[4]={q.x,q.y,q.z,q.w};
      float sn=0.f, sd=0.f;
      #pragma unroll
      for (int e=0;e<4;e++){
        float z=fmaf(A2[e],vi[e],B2[e]);
        float sg=frcp(1.f+fexp2(z));
        sd=fmaf(W2[e],sg,sd);
        sn=fmaf(E2[e],sg,sn);
      }
      sn += __shfl_xor(sn,1); sn += __shfl_xor(sn,2); sn += __shfl_xor(sn,4);
      sd += __shfl_xor(sd,1); sd += __shfl_xor(sd,2); sd += __shfl_xor(sd,4);
      vj2 = (fmaf(cmt2,vj2,bn2)+sn) * frcp(bd2+sd);
      p2x ^= 1;
      if (ig2==0) v2s[p2x][j2]=vj2;
      __syncthreads();
    }
  }

  if (tid<16){
    float o = fmaf(v2s[p2x][tid], a.ow2[tid], a.ob2[tid]) * a.fcw[tid];
    o += __shfl_xor(o,1); o += __shfl_xor(o,2); o += __shfl_xor(o,4); o += __shfl_xor(o,8);
    if (tid==0){
      float z = o + a.fcb[0];
      a.out[b] = frcp(1.f + fexp2(-z*LOG2E));
    }
  }
}

extern "C" void kernel_launch(void* const* d_in, const int* in_sizes, int n_in,
                              void* d_out, int out_size, void* d_ws, size_t ws_size,
                              hipStream_t stream)
{
  (void)out_size;
  int o[41];
  for (int i=0;i<41;i++) o[i]=i;
  if (n_in>=41 && in_sizes[20]!=4096){
    for (int i=0;i<15;i++) o[5+i]=5+i;
    o[20]=37; o[21]=38;
    for (int i=0;i<15;i++) o[22+i]=20+i;
    o[37]=39; o[38]=40;
    o[39]=35; o[40]=36;
  }
  const float* F[41];
  for (int i=0;i<41;i++) F[i]=(const float*)d_in[o[i]];
  LtcArgs a;
  a.x=F[0]; a.c1w=F[1]; a.c1b=F[2]; a.c2w=F[3]; a.c2b=F[4];
  a.g1=F[5]; a.vl1=F[6]; a.cm1=F[7]; a.sg1=F[8]; a.mu1=F[9]; a.w1=F[10]; a.er1=F[11];
  a.ssg1=F[12]; a.smu1=F[13]; a.sw1=F[14]; a.ser1=F[15];
  a.iw1=F[16]; a.ib1=F[17]; a.ow1=F[18]; a.ob1=F[19];
  a.mk1=(const void*)d_in[o[20]]; a.smk1=(const void*)d_in[o[21]];
  a.g2=F[22]; a.vl2=F[23]; a.cm2=F[24]; a.sg2=F[25]; a.mu2=F[26]; a.w2=F[27]; a.er2=F[28];
  a.ssg2=F[29]; a.smu2=F[30]; a.sw2=F[31]; a.ser2=F[32];
  a.iw2=F[33]; a.ib2=F[34]; a.ow2=F[35]; a.ob2=F[36];
  a.mk2=(const void*)d_in[o[37]]; a.smk2=(const void*)d_in[o[38]];
  a.fcw=F[39]; a.fcb=F[40];
  a.out=(float*)d_out;

  const size_t need = 256 + (size_t)256*1024*64*sizeof(float2);
  if (ws_size >= need){
    int* hdr = (int*)d_ws;
    float2* pre = (float2*)((char*)d_ws + 256);
    ltc_modes<<<dim3(1),dim3(256),0,stream>>>(a.mk1,a.smk1,a.mk2,a.smk2,hdr);
    ltc_pre<<<dim3(256,16),dim3(256),0,stream>>>(a,hdr,pre);
    ltc_scan<<<dim3(256),dim3(512),0,stream>>>(a,pre,hdr);
  } else {
    ltc_fused<<<dim3(256),dim3(256),0,stream>>>(a);
  }
}

// Round 10
// 3545.123 us; speedup vs baseline: 1.4644x; 1.0087x over previous
//
#include <hip/hip_runtime.h>
#include <stdint.h>

#define LOG2E 1.44269504088896340736f

struct LtcArgs {
  const float *x, *c1w, *c1b, *c2w, *c2b;
  const float *g1,*vl1,*cm1,*sg1,*mu1,*w1,*er1,*ssg1,*smu1,*sw1,*ser1,*iw1,*ib1,*ow1,*ob1;
  const void  *mk1,*smk1;
  const float *g2,*vl2,*cm2,*sg2,*mu2,*w2,*er2,*ssg2,*smu2,*sw2,*ser2,*iw2,*ib2,*ow2,*ob2;
  const void  *mk2,*smk2;
  const float *fcw,*fcb;
  float *out;
};

__device__ __forceinline__ float fexp2(float v){ return __builtin_amdgcn_exp2f(v); }
__device__ __forceinline__ float frcp (float v){ return __builtin_amdgcn_rcpf(v); }
// per-lane variable gather within the wave (ds_bpermute); index is PRE-SHIFTED byte addr
__device__ __forceinline__ float gatherb(float v, int byteLane){
  return __int_as_float(__builtin_amdgcn_ds_bpermute(byteLane, __float_as_int(v)));
}
__device__ __forceinline__ int wave_max(int v){
  #pragma unroll
  for (int s=1;s<64;s<<=1){ int o=__shfl_xor(v,s); v = o>v ? o : v; }
  return __builtin_amdgcn_readfirstlane(v);
}

// Raw barrier with LDS-only drain (learn_hip m194-m201 pattern). __syncthreads
// emits s_waitcnt vmcnt(0) lgkmcnt(0) before s_barrier; the vmcnt(0) drains
// our in-flight global `pre` prefetch (~300cy exposed per timestep) and pays
// full-drain sequencing 6156 times. LDS producer->consumer ordering (p1/p2/
// pb/v1buf) only needs lgkmcnt(0). "memory" clobber stops the compiler from
// hoisting LDS ops across (consumers are real memory ops, so the clobber
// orders them — rule 18 applies only to register-only MFMA consumers).
__device__ __forceinline__ void bar_lgkm(){
  asm volatile("s_waitcnt lgkmcnt(0)" ::: "memory");
  __builtin_amdgcn_s_barrier();
  asm volatile("" ::: "memory");
}

// ---- mask dtype detection (verified: absmax 0) ----
__device__ __forceinline__ void scan_mask(const void* p, int n, int tid, int* cge2, int* cone){
  const uint8_t* bp = (const uint8_t*)p;
  int g=0,o=0;
  for (int k=tid;k<n;k+=256){ uint8_t v=bp[k]; g += (v>=2); o += (v==1); }
  if (g) atomicAdd(cge2,g);
  if (o) atomicAdd(cone,o);
}
__device__ __forceinline__ int decide_mode(int ge2,int one,int n){
  if (ge2 > (n>>4)) return 2;
  if (one > (n>>2)) return 0;
  return 1;
}
__device__ __forceinline__ float mask_at(const void* p,int mode,int idx){
  if (mode==2) return ((const float*)p)[idx]!=0.f ? 1.f:0.f;
  if (mode==1) return ((const int*)p)[idx]!=0 ? 1.f:0.f;
  return ((const uint8_t*)p)[idx]!=0 ? 1.f:0.f;
}

// ================= kernel 0: mask modes -> hdr =================
__global__ void ltc_modes(const void* mk1,const void* smk1,const void* mk2,const void* smk2,int* hdr){
  __shared__ int cnt[8];
  const int tid=threadIdx.x;
  if (tid<8) cnt[tid]=0;
  __syncthreads();
  scan_mask(mk1, 4096, tid, &cnt[0], &cnt[1]);
  scan_mask(smk1,2048, tid, &cnt[2], &cnt[3]);
  scan_mask(mk2, 1024, tid, &cnt[4], &cnt[5]);
  scan_mask(smk2,1024, tid, &cnt[6], &cnt[7]);
  __syncthreads();
  if (tid==0){
    hdr[0]=decide_mode(cnt[0],cnt[1],4096);
    hdr[1]=decide_mode(cnt[2],cnt[3],2048);
    hdr[2]=decide_mode(cnt[4],cnt[5],1024);
    hdr[3]=decide_mode(cnt[6],cnt[7],1024);
  }
}

// ================= kernel 1: precompute conv + L1 synapse sums =================
__global__ __launch_bounds__(256,2)
void ltc_pre(LtcArgs a, const int* __restrict__ hdr, float2* __restrict__ pre)
{
  const int b=blockIdx.x, tb=blockIdx.y*64, tid=threadIdx.x;
  const int mds1=hdr[1];
  __shared__ float us[4][32];

  const int j = tid&63;
  float As[32],Bs[32],Ws[32],Es[32];
  #pragma unroll
  for (int e=0;e<32;e++){
    const int idx=e*64+j;
    const float s=a.ssg1[idx];
    As[e]=-s*LOG2E; Bs[e]=s*a.smu1[idx]*LOG2E;
    const float wm=a.sw1[idx]*mask_at(a.smk1,mds1,idx);
    Ws[e]=wm; Es[e]=wm*a.ser1[idx];
  }
  const int th=tid>>5, f=tid&31, cc=f>>2, cwp=f&3;
  float k1[12],b1[4],k2[12],cb2=0.f,wi=0.f,bi=0.f;
  if (tid<128){
    #pragma unroll
    for (int q=0;q<12;q++) k1[q]=a.c1w[q];
    #pragma unroll
    for (int q=0;q<4;q++)  b1[q]=a.c1b[q];
    #pragma unroll
    for (int q=0;q<12;q++) k2[q]=a.c2w[cc*12+q];
    cb2=a.c2b[cc]; wi=a.iw1[f]; bi=a.ib1[f];
  }

  for (int tt=0; tt<64; tt+=4){
    if (tid<128){
      const int t=tb+tt+th;
      const float4* xg=(const float4*)(a.x + ((size_t)b*1024 + t)*8);
      float4 xa=xg[0], xb=xg[1];
      float xr[8]={xa.x,xa.y,xa.z,xa.w,xb.x,xb.y,xb.z,xb.w};
      float acc=cb2;
      #pragma unroll
      for (int ci=0;ci<4;ci++){
        const float q0=k1[ci*3],q1=k1[ci*3+1],q2=k1[ci*3+2],bb=b1[ci];
        #pragma unroll
        for (int kk=0;kk<3;kk++){
          const int p=cwp+kk;
          float h=fmaf(q0,xr[p],fmaf(q1,xr[p+1],fmaf(q2,xr[p+2],bb)));
          h=fmaxf(h,0.f);
          acc=fmaf(k2[ci*3+kk],h,acc);
        }
      }
      us[th][f]=fmaf(acc,wi,bi);
    }
    __syncthreads();
    {
      const int t4=tid>>6;
      float wns=0.f,wds=0.f;
      #pragma unroll
      for (int e=0;e<32;e++){
        const float u=us[t4][e];
        const float z=fmaf(As[e],u,Bs[e]);
        const float sg=frcp(1.f+fexp2(z));
        wds=fmaf(Ws[e],sg,wds);
        wns=fmaf(Es[e],sg,wns);
      }
      pre[((size_t)((b<<10)+tb+tt+t4))*64 + j] = make_float2(wns,wds);
    }
    __syncthreads();
  }
}

// ================= kernel 2: sequential scan (R0-verified structure) =================
// 256 blocks x 512 thr. Waves 0-3: L1 (lane=neuron, ranks mod 4, 11 uncond
// compacted slots + rare guarded tail). Waves 4-7: L2 pipelined one step
// behind, 4 unconditional slots. This 4+4 / 2-waves-per-SIMD layout is the
// measured local optimum (R2/R4/R6/R7 restructures all regressed; R3 LDS
// float atomics catastrophic; R8 setprio regressed 2.5%). R10 change:
// per-segment barrier = lgkm-only raw barrier (bar_lgkm) — removes the
// vmcnt(0) drain that serialized the global `pre` prefetch into every
// timestep's k==1 barrier, and the full-drain sequencing on all 6156
// barriers. LDS ordering preserved by lgkmcnt(0).
__global__ __launch_bounds__(512,1)
void ltc_scan(LtcArgs a, const float2* __restrict__ pre, const int* __restrict__ hdr)
{
  const int b=blockIdx.x, tid=threadIdx.x;
  const int w=tid>>6, l=tid&63;
  const bool L1g = (w<4);

  __shared__ float2 p1[2][4][64];    // L1 partials (sn,sd)
  __shared__ float2 p2[2][8][32];    // L2 unfold partials
  __shared__ float2 pb[8][32];       // L2 synapse partials
  __shared__ float  v1buf[64];

  const int md1=hdr[0], md2=hdr[2], mds2=hdr[3];

  // L1 compacted: 16 slots, wave w takes ranks == w (mod 4); zero-padded.
  float A[16],B[16],W[16],E[16]; int I[16];
  // L2 compacted: 4 slots each (ranks == c mod 8 over 32 inputs); zero-padded.
  float A2[4],B2[4],W2[4],E2[4]; int I2[4];
  float As2[4],Bs2[4],Ws2[4],Es2[4]; int Is2[4];
  float cmt,gl,gv;
  int j2=0, c=0;
  int c1max=0;
  float2 cur=make_float2(0.f,0.f), nxt=make_float2(0.f,0.f);

  if (L1g){
    #pragma unroll
    for (int q=0;q<16;q++){ A[q]=0.f;B[q]=0.f;W[q]=0.f;E[q]=0.f;I[q]=0; }
    unsigned long long mm=0ull;
    for (int e=0;e<64;e++)
      if (mask_at(a.mk1,md1,e*64+l)!=0.f) mm |= (1ull<<e);
    int r=0, cnt=0;
    while (mm){
      const int e=(int)__builtin_ctzll(mm); mm&=mm-1;
      if ((r&3)==w && cnt<16){
        const int idx=e*64+l;
        const float s=a.sg1[idx];
        A[cnt]=-s*LOG2E; B[cnt]=s*a.mu1[idx]*LOG2E;
        const float wmv=a.w1[idx];
        W[cnt]=wmv; E[cnt]=wmv*a.er1[idx];
        I[cnt]=e<<2;                      // pre-shifted bpermute byte index
        cnt++;
      }
      r++;
    }
    c1max = wave_max(cnt);
    cmt=a.cm1[l]*6.f; gl=a.g1[l]; gv=gl*a.vl1[l];
    cur = pre[((size_t)(b<<10))*64 + l];
  } else {
    j2 = l&31; c = ((w-4)<<1) + (l>>5);
    #pragma unroll
    for (int q=0;q<4;q++){ A2[q]=0.f;B2[q]=0.f;W2[q]=0.f;E2[q]=0.f;I2[q]=0;
                           As2[q]=0.f;Bs2[q]=0.f;Ws2[q]=0.f;Es2[q]=0.f;Is2[q]=0; }
    { // main synapse (mk2): ranks == c (mod 8); 4 slots covers nnz<=32 exactly
      unsigned mm=0u;
      for (int e=0;e<32;e++)
        if (mask_at(a.mk2,md2,e*32+j2)!=0.f) mm |= (1u<<e);
      int r=0, cnt=0;
      while (mm){
        const int e=(int)__builtin_ctz(mm); mm&=mm-1;
        if ((r&7)==c && cnt<4){
          const int idx=e*32+j2;
          const float s=a.sg2[idx];
          A2[cnt]=-s*LOG2E; B2[cnt]=s*a.mu2[idx]*LOG2E;
          const float wmv=a.w2[idx];
          W2[cnt]=wmv; E2[cnt]=wmv*a.er2[idx];
          I2[cnt]=e<<2;                   // pre-shifted bpermute byte index
          cnt++;
        }
        r++;
      }
    }
    { // sensory synapse (smk2), input-affine folded (verified)
      unsigned mm=0u;
      for (int e=0;e<32;e++)
        if (mask_at(a.smk2,mds2,e*32+j2)!=0.f) mm |= (1u<<e);
      int r=0, cnt=0;
      while (mm){
        const int e=(int)__builtin_ctz(mm); mm&=mm-1;
        if ((r&7)==c && cnt<4){
          const int idx=e*32+j2;
          const float s=a.ssg2[idx];
          float Aq=-s*LOG2E, Bq=s*a.smu2[idx]*LOG2E;
          const float wi=a.ow1[e]*a.iw2[e];
          const float ci=fmaf(a.ob1[e],a.iw2[e],a.ib2[e]);
          Bq=fmaf(Aq,ci,Bq); Aq*=wi;
          As2[cnt]=Aq; Bs2[cnt]=Bq;
          const float wmv=a.sw2[idx];
          Ws2[cnt]=wmv; Es2[cnt]=wmv*a.ser2[idx];
          Is2[cnt]=e;                     // LDS index (unshifted)
          cnt++;
        }
        r++;
      }
    }
    cmt=a.cm2[j2]*6.f; gl=a.g2[j2]; gv=gl*a.vl2[j2];
  }

  float v1=0.f, v2=0.f;
  float bn=0.f, bdb=1.f;

  #pragma unroll 1
  for (int t=0;t<1026;t++){
    const bool l1act = L1g && (t<1024);
    const bool l2syn = (!L1g) && (t>=1) && (t<=1024);
    const bool l2u5  = (!L1g) && (t>=2);
    #pragma unroll
    for (int k=0;k<6;k++){
      const int buf = k&1;
      // ---------- pre-barrier: partial sums ----------
      if (l1act){
        float sn0=0.f,sn1=0.f,sd0=0.f,sd1=0.f;
        #pragma unroll
        for (int q=0;q<11;q++){            // branch-free common path
          const float vv=gatherb(v1, I[q]);
          const float z=fmaf(A[q],vv,B[q]);
          const float sg=frcp(1.f+fexp2(z));
          if (q&1){ sd1=fmaf(W[q],sg,sd1); sn1=fmaf(E[q],sg,sn1); }
          else    { sd0=fmaf(W[q],sg,sd0); sn0=fmaf(E[q],sg,sn0); }
        }
        if (c1max>11){                      // rare tail (nnz>44 in some column)
          #pragma unroll
          for (int q=11;q<16;q++){
            if (q<c1max){
              const float vv=gatherb(v1, I[q]);
              const float z=fmaf(A[q],vv,B[q]);
              const float sg=frcp(1.f+fexp2(z));
              sd0=fmaf(W[q],sg,sd0); sn0=fmaf(E[q],sg,sn0);
            }
          }
        }
        p1[buf][w][l]=make_float2(sn0+sn1, sd0+sd1);
      } else if (!L1g){
        const bool go = (k==0) ? l2u5 : l2syn;
        if (go){
          float sn=0.f, sd=0.f;
          #pragma unroll
          for (int q=0;q<4;q++){            // branch-free
            const float vv=gatherb(v2, I2[q]);
            const float z=fmaf(A2[q],vv,B2[q]);
            const float sg=frcp(1.f+fexp2(z));
            sd=fmaf(W2[q],sg,sd);
            sn=fmaf(E2[q],sg,sn);
          }
          p2[buf][c][j2]=make_float2(sn,sd);
        }
      }
      bar_lgkm();
      // ---------- post-barrier: reductions + state update ----------
      if (l1act){
        if (k==0){
          bn = gv + cur.x;
          bdb = cmt + gl + cur.y + 1e-8f;
          if (t+1<1024) nxt = pre[((size_t)((b<<10)+t+1))*64 + l];
        }
        const float2 q0=p1[buf][0][l], q1=p1[buf][1][l], q2=p1[buf][2][l], q3=p1[buf][3][l];
        const float sn = (q0.x+q1.x)+(q2.x+q3.x);
        const float sd = (q0.y+q1.y)+(q2.y+q3.y);
        v1 = (fmaf(cmt,v1,bn)+sn) * frcp(bdb+sd);
        if (k==5){
          if (w==0) v1buf[l]=v1;
          cur=nxt;
        }
      } else if (!L1g){
        if (k==0){
          if (l2u5){
            float2 s0=p2[buf][0][j2], s1=p2[buf][1][j2], s2=p2[buf][2][j2], s3=p2[buf][3][j2];
            float2 s4=p2[buf][4][j2], s5=p2[buf][5][j2], s6=p2[buf][6][j2], s7=p2[buf][7][j2];
            const float sn=((s0.x+s1.x)+(s2.x+s3.x))+((s4.x+s5.x)+(s6.x+s7.x));
            const float sd=((s0.y+s1.y)+(s2.y+s3.y))+((s4.y+s5.y)+(s6.y+s7.y));
            v2 = (fmaf(cmt,v2,bn)+sn) * frcp(bdb+sd);   // finishes step t-2
          }
          if (l2syn){
            float ssn=0.f, ssd=0.f;
            #pragma unroll
            for (int q=0;q<4;q++){          // branch-free
              const float vb=v1buf[Is2[q]];              // v1(t-1)
              const float z=fmaf(As2[q],vb,Bs2[q]);
              const float sg=frcp(1.f+fexp2(z));
              ssd=fmaf(Ws2[q],sg,ssd);
              ssn=fmaf(Es2[q],sg,ssn);
            }
            pb[c][j2]=make_float2(ssn,ssd);
          }
        }
        if (k>=1 && l2syn){
          if (k==1){
            float2 s0=pb[0][j2], s1=pb[1][j2], s2=pb[2][j2], s3=pb[3][j2];
            float2 s4=pb[4][j2], s5=pb[5][j2], s6=pb[6][j2], s7=pb[7][j2];
            const float wns=((s0.x+s1.x)+(s2.x+s3.x))+((s4.x+s5.x)+(s6.x+s7.x));
            const float wds=((s0.y+s1.y)+(s2.y+s3.y))+((s4.y+s5.y)+(s6.y+s7.y));
            bn = gv + wns;
            bdb = cmt + gl + wds + 1e-8f;
          }
          float2 s0=p2[buf][0][j2], s1=p2[buf][1][j2], s2=p2[buf][2][j2], s3=p2[buf][3][j2];
          float2 s4=p2[buf][4][j2], s5=p2[buf][5][j2], s6=p2[buf][6][j2], s7=p2[buf][7][j2];
          const float sn=((s0.x+s1.x)+(s2.x+s3.x))+((s4.x+s5.x)+(s6.x+s7.x));
          const float sd=((s0.y+s1.y)+(s2.y+s3.y))+((s4.y+s5.y)+(s6.y+s7.y));
          v2 = (fmaf(cmt,v2,bn)+sn) * frcp(bdb+sd);     // unfold k-1 of step t-1
        }
      }
    }
  }

  if (w==4 && l<16){
    float o = fmaf(v2, a.ow2[l], a.ob2[l]) * a.fcw[l];
    o += __shfl_xor(o,1); o += __shfl_xor(o,2); o += __shfl_xor(o,4); o += __shfl_xor(o,8);
    if (l==0){
      const float z = o + a.fcb[0];
      a.out[b] = frcp(1.f + fexp2(-z*LOG2E));
    }
  }
}

// ================= fallback: fused kernel (verified) =================
__global__ __launch_bounds__(256,1)
void ltc_fused(LtcArgs a)
{
  const int b=blockIdx.x, tid=threadIdx.x;
  __shared__ __align__(16) float xs[8192];
  __shared__ __align__(16) float v1s[2][64];
  __shared__ __align__(16) float v2s[2][32];
  __shared__ __align__(16) float u1s[8][32];
  __shared__ float cwts[184];
  __shared__ int cnt[8];

  {
    const float4* xg=(const float4*)(a.x + (size_t)b*8192);
    float4* xd=(float4*)xs;
    #pragma unroll
    for (int k=0;k<8;k++) xd[tid+256*k]=xg[tid+256*k];
  }
  if (tid<8) cnt[tid]=0;
  if (tid<64){ v1s[0][tid]=0.f; v1s[1][tid]=0.f; }
  if (tid<32){ v2s[0][tid]=0.f; v2s[1][tid]=0.f; }
  if (tid<12) cwts[tid]=a.c1w[tid];
  else if (tid<16)  cwts[tid]=a.c1b[tid-12];
  else if (tid<112) cwts[tid]=a.c2w[tid-16];
  else if (tid<120) cwts[tid]=a.c2b[tid-112];
  else if (tid<152) cwts[tid]=a.iw1[tid-120];
  else if (tid<184) cwts[tid]=a.ib1[tid-152];
  __syncthreads();

  scan_mask(a.mk1, 4096, tid, &cnt[0], &cnt[1]);
  scan_mask(a.smk1,2048, tid, &cnt[2], &cnt[3]);
  scan_mask(a.mk2, 1024, tid, &cnt[4], &cnt[5]);
  scan_mask(a.smk2,1024, tid, &cnt[6], &cnt[7]);
  __syncthreads();
  const int md1 =decide_mode(cnt[0],cnt[1],4096);
  const int mds1=decide_mode(cnt[2],cnt[3],2048);
  const int md2 =decide_mode(cnt[4],cnt[5],1024);
  const int mds2=decide_mode(cnt[6],cnt[7],1024);

  const int j1=tid>>2, ig1=tid&3;
  float Au[16],Bu[16],Wu[16],Eu[16];
  #pragma unroll
  for (int e=0;e<16;e++){
    const int i=16*ig1+e, idx=i*64+j1;
    const float s=a.sg1[idx];
    Au[e]=-s*LOG2E; Bu[e]=s*a.mu1[idx]*LOG2E;
    const float wm=a.w1[idx]*mask_at(a.mk1,md1,idx);
    Wu[e]=wm; Eu[e]=wm*a.er1[idx];
  }
  float As[8],Bs[8],Ws[8],Es[8];
  #pragma unroll
  for (int e=0;e<8;e++){
    const int i=8*ig1+e, idx=i*64+j1;
    const float s=a.ssg1[idx];
    As[e]=-s*LOG2E; Bs[e]=s*a.smu1[idx]*LOG2E;
    const float wm=a.sw1[idx]*mask_at(a.smk1,mds1,idx);
    Ws[e]=wm; Es[e]=wm*a.ser1[idx];
  }
  const float cmt1=a.cm1[j1]*6.f, gl1=a.g1[j1], gv1=gl1*a.vl1[j1];

  const int j2=tid>>3, ig2=tid&7;
  float A2[4],B2[4],W2[4],E2[4],A2s[4],B2s[4],W2s[4],E2s[4],Wi2[4],Ci2[4];
  #pragma unroll
  for (int e=0;e<4;e++){
    const int i=4*ig2+e, idx=i*32+j2;
    { const float s=a.sg2[idx];
      A2[e]=-s*LOG2E; B2[e]=s*a.mu2[idx]*LOG2E;
      const float wm=a.w2[idx]*mask_at(a.mk2,md2,idx);
      W2[e]=wm; E2[e]=wm*a.er2[idx]; }
    { const float s=a.ssg2[idx];
      A2s[e]=-s*LOG2E; B2s[e]=s*a.smu2[idx]*LOG2E;
      const float wm=a.sw2[idx]*mask_at(a.smk2,mds2,idx);
      W2s[e]=wm; E2s[e]=wm*a.ser2[idx]; }
    Wi2[e]=a.ow1[i]*a.iw2[i];
    Ci2[e]=fmaf(a.ob1[i],a.iw2[i],a.ib2[i]);
  }
  const float cmt2=a.cm2[j2]*6.f, gl2=a.g2[j2], gv2=gl2*a.vl2[j2];

  float vj1=0.f, vj2=0.f;
  int p1x=0, p2x=0;
  const int cf=tid&31, cc=cf>>2, cwp=cf&3, ctc=tid>>5;

  for (int t=0;t<1024;t++){
    if ((t&7)==0){
      const float* xr = &xs[(t+ctc)*8];
      float acc = cwts[112+cc];
      #pragma unroll
      for (int ci=0;ci<4;ci++){
        const float k10=cwts[ci*3], k11=cwts[ci*3+1], k12=cwts[ci*3+2], bb=cwts[12+ci];
        #pragma unroll
        for (int kk=0;kk<3;kk++){
          const int p=cwp+kk;
          float h = fmaf(k10,xr[p], fmaf(k11,xr[p+1], fmaf(k12,xr[p+2], bb)));
          h = fmaxf(h,0.f);
          acc = fmaf(cwts[16+(cc*4+ci)*3+kk], h, acc);
        }
      }
      u1s[ctc][cf] = fmaf(acc, cwts[120+cf], cwts[152+cf]);
      __syncthreads();
    }

    float wns=0.f, wds=0.f;
    {
      const float4* uv4=(const float4*)&u1s[t&7][8*ig1];
      float4 qa=uv4[0], qb=uv4[1];
      float uvv[8]={qa.x,qa.y,qa.z,qa.w,qb.x,qb.y,qb.z,qb.w};
      #pragma unroll
      for (int e=0;e<8;e++){
        float z=fmaf(As[e],uvv[e],Bs[e]);
        float sg=frcp(1.f+fexp2(z));
        wds=fmaf(Ws[e],sg,wds);
        wns=fmaf(Es[e],sg,wns);
      }
      wns += __shfl_xor(wns,1); wns += __shfl_xor(wns,2);
      wds += __shfl_xor(wds,1); wds += __shfl_xor(wds,2);
    }
    const float bn1 = gv1 + wns;
    const float bd1 = cmt1 + gl1 + wds + 1e-8f;

    #pragma unroll
    for (int k=0;k<6;k++){
      const float4* vv4=(const float4*)&v1s[p1x][16*ig1];
      float4 q0=vv4[0], q1=vv4[1], q2=vv4[2], q3=vv4[3];
      float vi[16]={q0.x,q0.y,q0.z,q0.w,q1.x,q1.y,q1.z,q1.w,
                    q2.x,q2.y,q2.z,q2.w,q3.x,q3.y,q3.z,q3.w};
      float sn=0.f, sd=0.f;
      #pragma unroll
      for (int e=0;e<16;e++){
        float z=fmaf(Au[e],vi[e],Bu[e]);
        float sg=frcp(1.f+fexp2(z));
        sd=fmaf(Wu[e],sg,sd);
        sn=fmaf(Eu[e],sg,sn);
      }
      sn += __shfl_xor(sn,1); sn += __shfl_xor(sn,2);
      sd += __shfl_xor(sd,1); sd += __shfl_xor(sd,2);
      vj1 = (fmaf(cmt1,vj1,bn1)+sn) * frcp(bd1+sd);
      p1x ^= 1;
      if (ig1==0) v1s[p1x][j1]=vj1;
      __syncthreads();
    }

    float wns2=0.f, wds2=0.f;
    {
      const float4* vf4=(const float4*)&v1s[p1x][4*ig2];
      float4 vf=vf4[0];
      float vin[4]={vf.x,vf.y,vf.z,vf.w};
      #pragma unroll
      for (int e=0;e<4;e++){
        float u2=fmaf(vin[e],Wi2[e],Ci2[e]);
        float z=fmaf(A2s[e],u2,B2s[e]);
        float sg=frcp(1.f+fexp2(z));
        wds2=fmaf(W2s[e],sg,wds2);
        wns2=fmaf(E2s[e],sg,wns2);
      }
      wns2 += __shfl_xor(wns2,1); wns2 += __shfl_xor(wns2,2); wns2 += __shfl_xor(wns2,4);
      wds2 += __shfl_xor(wds2,1); wds2 += __shfl_xor(wds2,2); wds2 += __shfl_xor(wds2,4);
    }
    const float bn2 = gv2 + wns2;
    const float bd2 = cmt2 + gl2 + wds2 + 1e-8f;

    #pragma unroll
    for (int k=0;k<6;k++){
      const float4* vv4=(const float4*)&v2s[p2x][4*ig2];
      float4 q=vv4[0];
      float vi[4]={q.x,q.y,q.z,q.w};
      float sn=0.f, sd=0.f;
      #pragma unroll
      for (int e=0;e<4;e++){
        float z=fmaf(A2[e],vi[e],B2[e]);
        float sg=frcp(1.f+fexp2(z));
        sd=fmaf(W2[e],sg,sd);
        sn=fmaf(E2[e],sg,sn);
      }
      sn += __shfl_xor(sn,1); sn += __shfl_xor(sn,2); sn += __shfl_xor(sn,4);
      sd += __shfl_xor(sd,1); sd += __shfl_xor(sd,2); sd += __shfl_xor(sd,4);
      vj2 = (fmaf(cmt2,vj2,bn2)+sn) * frcp(bd2+sd);
      p2x ^= 1;
      if (ig2==0) v2s[p2x][j2]=vj2;
      __syncthreads();
    }
  }

  if (tid<16){
    float o = fmaf(v2s[p2x][tid], a.ow2[tid], a.ob2[tid]) * a.fcw[tid];
    o += __shfl_xor(o,1); o += __shfl_xor(o,2); o += __shfl_xor(o,4); o += __shfl_xor(o,8);
    if (tid==0){
      float z = o + a.fcb[0];
      a.out[b] = frcp(1.f + fexp2(-z*LOG2E));
    }
  }
}

extern "C" void kernel_launch(void* const* d_in, const int* in_sizes, int n_in,
                              void* d_out, int out_size, void* d_ws, size_t ws_size,
                              hipStream_t stream)
{
  (void)out_size;
  int o[41];
  for (int i=0;i<41;i++) o[i]=i;
  if (n_in>=41 && in_sizes[20]!=4096){
    for (int i=0;i<15;i++) o[5+i]=5+i;
    o[20]=37; o[21]=38;
    for (int i=0;i<15;i++) o[22+i]=20+i;
    o[37]=39; o[38]=40;
    o[39]=35; o[40]=36;
  }
  const float* F[41];
  for (int i=0;i<41;i++) F[i]=(const float*)d_in[o[i]];
  LtcArgs a;
  a.x=F[0]; a.c1w=F[1]; a.c1b=F[2]; a.c2w=F[3]; a.c2b=F[4];
  a.g1=F[5]; a.vl1=F[6]; a.cm1=F[7]; a.sg1=F[8]; a.mu1=F[9]; a.w1=F[10]; a.er1=F[11];
  a.ssg1=F[12]; a.smu1=F[13]; a.sw1=F[14]; a.ser1=F[15];
  a.iw1=F[16]; a.ib1=F[17]; a.ow1=F[18]; a.ob1=F[19];
  a.mk1=(const void*)d_in[o[20]]; a.smk1=(const void*)d_in[o[21]];
  a.g2=F[22]; a.vl2=F[23]; a.cm2=F[24]; a.sg2=F[25]; a.mu2=F[26]; a.w2=F[27]; a.er2=F[28];
  a.ssg2=F[29]; a.smu2=F[30]; a.sw2=F[31]; a.ser2=F[32];
  a.iw2=F[33]; a.ib2=F[34]; a.ow2=F[35]; a.ob2=F[36];
  a.mk2=(const void*)d_in[o[37]]; a.smk2=(const void*)d_in[o[38]];
  a.fcw=F[39]; a.fcb=F[40];
  a.out=(float*)d_out;

  const size_t need = 256 + (size_t)256*1024*64*sizeof(float2);
  if (ws_size >= need){
    int* hdr = (int*)d_ws;
    float2* pre = (float2*)((char*)d_ws + 256);
    ltc_modes<<<dim3(1),dim3(256),0,stream>>>(a.mk1,a.smk1,a.mk2,a.smk2,hdr);
    ltc_pre<<<dim3(256,16),dim3(256),0,stream>>>(a,hdr,pre);
    ltc_scan<<<dim3(256),dim3(512),0,stream>>>(a,pre,hdr);
  } else {
    ltc_fused<<<dim3(256),dim3(256),0,stream>>>(a);
  }
}